// Round 2
// baseline (1202.186 us; speedup 1.0000x reference)
//
#include <hip/hip_runtime.h>
#include <hip/hip_bf16.h>
#include <math.h>

#define B_   2
#define T_   1024
#define H_   2048
#define NH_  8
#define NKV_ 2
#define HD_  256
#define S_   4
#define FF_  8192
#define LR_  64
#define ROWS_ (B_*T_)          // 2048 tokens
#define EPS_ 1e-6f

typedef __attribute__((ext_vector_type(8))) __bf16 bf16x8;
typedef __attribute__((ext_vector_type(4))) float floatx4;
typedef __attribute__((ext_vector_type(8))) unsigned short ushort8v;

__device__ __forceinline__ unsigned short f2bf(float f) {
    unsigned int u = __float_as_uint(f);
    return (unsigned short)((u + 0x7FFFu + ((u >> 16) & 1u)) >> 16);
}

// async global->LDS, 16B per lane. LDS dest is wave-uniform base + lane*16.
__device__ __forceinline__ void gl_lds16(const void* g, void* l) {
    __builtin_amdgcn_global_load_lds(
        (const __attribute__((address_space(1))) void*)g,
        (__attribute__((address_space(3))) void*)l, 16, 0, 0);
}

// ---------------- block-wide reductions (256 threads = 4 waves) ----------------
__device__ __forceinline__ float block_sum(float v) {
    __shared__ float s4[4];
    #pragma unroll
    for (int o = 32; o > 0; o >>= 1) v += __shfl_down(v, o, 64);
    int lane = threadIdx.x & 63;
    int w    = threadIdx.x >> 6;
    __syncthreads();
    if (lane == 0) s4[w] = v;
    __syncthreads();
    return s4[0] + s4[1] + s4[2] + s4[3];
}

__device__ __forceinline__ float block_max(float v) {
    __shared__ float s4m[4];
    #pragma unroll
    for (int o = 32; o > 0; o >>= 1) v = fmaxf(v, __shfl_down(v, o, 64));
    int lane = threadIdx.x & 63;
    int w    = threadIdx.x >> 6;
    __syncthreads();
    if (lane == 0) s4m[w] = v;
    __syncthreads();
    return fmaxf(fmaxf(s4m[0], s4m[1]), fmaxf(s4m[2], s4m[3]));
}

// ---------------- fp32 -> bf16 convert (8 elements/thread) ----------------------
__global__ __launch_bounds__(256) void cvt_bf16(
    const float* __restrict__ in, unsigned short* __restrict__ out, int n)
{
    int i = (blockIdx.x * 256 + threadIdx.x) * 8;
    if (i >= n) return;
    float4 v0 = *reinterpret_cast<const float4*>(in + i);
    float4 v1 = *reinterpret_cast<const float4*>(in + i + 4);
    ushort8v o;
    o[0] = f2bf(v0.x); o[1] = f2bf(v0.y); o[2] = f2bf(v0.z); o[3] = f2bf(v0.w);
    o[4] = f2bf(v1.x); o[5] = f2bf(v1.y); o[6] = f2bf(v1.z); o[7] = f2bf(v1.w);
    *reinterpret_cast<ushort8v*>(out + i) = o;
}

// ---------------- router: m = tanh( (LN(x)*w_norm / H) @ router_w^T ) ----------
__global__ __launch_bounds__(256) void router_kernel(
    const float* __restrict__ x, const float* __restrict__ nw,
    const float* __restrict__ rw, float* __restrict__ mout)
{
    size_t row = blockIdx.x;
    int tid = threadIdx.x;
    const float* xr = x + row * H_;
    float v[8]; float s = 0.f;
    #pragma unroll
    for (int i = 0; i < 8; ++i) { v[i] = xr[i*256 + tid]; s += v[i]; }
    float mu = block_sum(s) * (1.f / H_);
    float ss = 0.f;
    #pragma unroll
    for (int i = 0; i < 8; ++i) { float c = v[i] - mu; ss += c * c; }
    float rstd = rsqrtf(block_sum(ss) * (1.f / H_) + EPS_);
    float n[8];
    #pragma unroll
    for (int i = 0; i < 8; ++i) n[i] = (v[i] - mu) * rstd * nw[i*256 + tid];
    for (int so = 0; so < S_; ++so) {
        float p = 0.f;
        #pragma unroll
        for (int i = 0; i < 8; ++i) p += n[i] * rw[(size_t)so * H_ + i*256 + tid];
        float dot = block_sum(p);
        if (tid == 0) mout[row * S_ + so] = tanhf(dot * (1.f / H_));
    }
}

// ---------------- altup predict ----------------
__global__ __launch_bounds__(256) void predict_kernel(
    const float* __restrict__ hid, const float* __restrict__ m,
    const float* __restrict__ pcw, float* __restrict__ pred)
{
    size_t row = blockIdx.x;
    int tid = threadIdx.x;
    __shared__ float ms[4];
    __shared__ float c[16];
    if (tid < 4) ms[tid] = m[row * S_ + tid];
    __syncthreads();
    if (tid < 16) {
        float s = 0.f;
        #pragma unroll
        for (int i = 0; i < 4; ++i) s += ms[i] * pcw[tid * 4 + i];
        c[tid] = s;
    }
    __syncthreads();
    const size_t STRIDE = (size_t)ROWS_ * H_;
    #pragma unroll
    for (int i = 0; i < 8; ++i) {
        size_t idx = row * H_ + i*256 + tid;
        float h0 = hid[idx];
        float h1 = hid[idx + STRIDE];
        float h2 = hid[idx + 2*STRIDE];
        float h3 = hid[idx + 3*STRIDE];
        float hv[4] = {h0, h1, h2, h3};
        #pragma unroll
        for (int j = 0; j < 4; ++j) {
            float val = hv[j] + h0*c[j*4+0] + h1*c[j*4+1] + h2*c[j*4+2] + h3*c[j*4+3];
            pred[idx + (size_t)j * STRIDE] = val;
        }
    }
}

// ---- LN (+ optional pre-add xadd, residuals a1/a2, scale, fp32/bf16 out) -------
__global__ __launch_bounds__(256) void ln_residual(
    const float* __restrict__ x, const float* __restrict__ xadd,
    const float* __restrict__ w,
    const float* __restrict__ a1, const float* __restrict__ a2,
    float scale, float* __restrict__ out, unsigned short* __restrict__ outb)
{
    size_t row = blockIdx.x;
    int tid = threadIdx.x;
    const float* xr = x + row * H_;
    const float* xa = xadd ? xadd + row * H_ : nullptr;
    float v[8]; float s = 0.f;
    #pragma unroll
    for (int i = 0; i < 8; ++i) {
        v[i] = xr[i*256 + tid];
        if (xa) v[i] += xa[i*256 + tid];
        s += v[i];
    }
    float mu = block_sum(s) * (1.f / H_);
    float ss = 0.f;
    #pragma unroll
    for (int i = 0; i < 8; ++i) { float c = v[i] - mu; ss += c * c; }
    float rstd = rsqrtf(block_sum(ss) * (1.f / H_) + EPS_);
    #pragma unroll
    for (int i = 0; i < 8; ++i) {
        size_t idx = row * H_ + i*256 + tid;
        float y = (v[i] - mu) * rstd * w[i*256 + tid];
        if (a1) y += a1[idx];
        if (a2) y += a2[idx];
        y *= scale;
        if (out)  out[idx]  = y;
        if (outb) outb[idx] = f2bf(y);
    }
}

// ---------------- fp32 GEMM (laurel only): C = A[M,K] * B[N,K]^T ----------------
#define BM 64
#define BN 64
#define BK 32
#define LDP 68

__global__ __launch_bounds__(256) void gemm_nt(
    const float* __restrict__ A, const float* __restrict__ Bm,
    float* __restrict__ C, int M, int N, int K)
{
    __shared__ float As[BK][LDP];
    __shared__ float Bs[BK][LDP];
    int tid = threadIdx.x;
    int n0 = blockIdx.x * BN;
    int m0 = blockIdx.y * BM;
    int tx = tid & 15, ty = tid >> 4;
    int lrow = tid >> 3;
    int lk   = (tid & 7) << 2;
    float acc[4][4] = {};
    for (int k0 = 0; k0 < K; k0 += BK) {
        #pragma unroll
        for (int r = 0; r < 2; ++r) {
            int row = lrow + r * 32;
            float4 a4 = *reinterpret_cast<const float4*>(&A[(size_t)(m0 + row) * K + k0 + lk]);
            As[lk+0][row] = a4.x; As[lk+1][row] = a4.y; As[lk+2][row] = a4.z; As[lk+3][row] = a4.w;
            float4 b4 = *reinterpret_cast<const float4*>(&Bm[(size_t)(n0 + row) * K + k0 + lk]);
            Bs[lk+0][row] = b4.x; Bs[lk+1][row] = b4.y; Bs[lk+2][row] = b4.z; Bs[lk+3][row] = b4.w;
        }
        __syncthreads();
        #pragma unroll
        for (int k = 0; k < BK; ++k) {
            float4 av = *reinterpret_cast<const float4*>(&As[k][ty << 2]);
            float4 bv = *reinterpret_cast<const float4*>(&Bs[k][tx << 2]);
            float a[4] = {av.x, av.y, av.z, av.w};
            float b[4] = {bv.x, bv.y, bv.z, bv.w};
            #pragma unroll
            for (int i = 0; i < 4; ++i)
                #pragma unroll
                for (int j = 0; j < 4; ++j)
                    acc[i][j] = fmaf(a[i], b[j], acc[i][j]);
        }
        __syncthreads();
    }
    #pragma unroll
    for (int i = 0; i < 4; ++i) {
        float4 o; o.x = acc[i][0]; o.y = acc[i][1]; o.z = acc[i][2]; o.w = acc[i][3];
        *reinterpret_cast<float4*>(&C[(size_t)(m0 + (ty << 2) + i) * N + n0 + (tx << 2)]) = o;
    }
}

// ---------------- bf16 MFMA GEMM, m97-style global_load_lds staging -------------
// C[M,N] (fp32) = A_bf16[M,K] * B_bf16[N,K]^T.  128x128 tile, BK=32.
// grid.z = split-K: z==0 -> C, z==1 -> C2 (consumer sums).
__global__ __launch_bounds__(256) void gemm_bf16nt(
    const unsigned short* __restrict__ A, const unsigned short* __restrict__ Bm,
    float* __restrict__ C, float* __restrict__ C2, int M, int N, int K)
{
    __shared__ unsigned short As[4096];   // [kc:4][m:128][8]
    __shared__ unsigned short Bs[4096];
    int tid = threadIdx.x;
    int lane = tid & 63;
    int wave = tid >> 6;
    int m0 = blockIdx.y * 128, n0 = blockIdx.x * 128;
    int Kper = K / gridDim.z;
    int kbeg = blockIdx.z * Kper;
    int kend = kbeg + Kper;
    int wm = (wave >> 1) * 64;
    int wn = (wave & 1) * 64;
    floatx4 acc[4][4] = {};

    // staging: wave w owns k-chunk w (8 shorts), lanes map to rows
    const unsigned short* aG0 = A  + (size_t)(m0 + lane)      * K + wave * 8;
    const unsigned short* aG1 = A  + (size_t)(m0 + 64 + lane) * K + wave * 8;
    const unsigned short* bG0 = Bm + (size_t)(n0 + lane)      * K + wave * 8;
    const unsigned short* bG1 = Bm + (size_t)(n0 + 64 + lane) * K + wave * 8;
    unsigned short* aL0 = &As[wave * 1024];
    unsigned short* aL1 = &As[wave * 1024 + 512];
    unsigned short* bL0 = &Bs[wave * 1024];
    unsigned short* bL1 = &Bs[wave * 1024 + 512];

    int kc = lane >> 4, mr = lane & 15;
    for (int k0 = kbeg; k0 < kend; k0 += 32) {
        __syncthreads();
        gl_lds16(aG0 + k0, aL0);
        gl_lds16(aG1 + k0, aL1);
        gl_lds16(bG0 + k0, bL0);
        gl_lds16(bG1 + k0, bL1);
        __syncthreads();   // drains vmcnt -> tile complete
        bf16x8 af[4], bfv[4];
        #pragma unroll
        for (int mi = 0; mi < 4; ++mi)
            af[mi] = *reinterpret_cast<const bf16x8*>(&As[kc * 1024 + (wm + mi * 16 + mr) * 8]);
        #pragma unroll
        for (int ni = 0; ni < 4; ++ni)
            bfv[ni] = *reinterpret_cast<const bf16x8*>(&Bs[kc * 1024 + (wn + ni * 16 + mr) * 8]);
        #pragma unroll
        for (int mi = 0; mi < 4; ++mi)
            #pragma unroll
            for (int ni = 0; ni < 4; ++ni)
                acc[mi][ni] = __builtin_amdgcn_mfma_f32_16x16x32_bf16(af[mi], bfv[ni], acc[mi][ni], 0, 0, 0);
    }
    float* Cout = (blockIdx.z == 0) ? C : C2;
    int quad = lane >> 4;
    #pragma unroll
    for (int mi = 0; mi < 4; ++mi)
        #pragma unroll
        for (int ni = 0; ni < 4; ++ni)
            #pragma unroll
            for (int r = 0; r < 4; ++r)
                Cout[(size_t)(m0 + wm + mi * 16 + quad * 4 + r) * N + n0 + wn + ni * 16 + mr] = acc[mi][ni][r];
}

// ---------------- fused gate/up bf16 GEMM -> gu_bf16 = gelu(A*G^T)*(A*U^T) ------
// BM=128, BN=64, BK=32; global_load_lds staging; 4 waves each 32 rows x 64 cols
__global__ __launch_bounds__(256) void gemm_gateup_bf16(
    const unsigned short* __restrict__ A, const unsigned short* __restrict__ G,
    const unsigned short* __restrict__ U, unsigned short* __restrict__ Cbf,
    int M, int N, int K)
{
    __shared__ unsigned short As[4096];  // [kc:4][m:128][8]
    __shared__ unsigned short Gs[2048];  // [kc:4][n:64][8]
    __shared__ unsigned short Us[2048];
    int tid = threadIdx.x;
    int lane = tid & 63;
    int wave = tid >> 6;
    int m0 = blockIdx.y * 128, n0 = blockIdx.x * 64;
    floatx4 accg[2][4] = {};
    floatx4 accu[2][4] = {};

    const unsigned short* aG0 = A + (size_t)(m0 + lane)      * K + wave * 8;
    const unsigned short* aG1 = A + (size_t)(m0 + 64 + lane) * K + wave * 8;
    const unsigned short* gG  = G + (size_t)(n0 + lane)      * K + wave * 8;
    const unsigned short* uG  = U + (size_t)(n0 + lane)      * K + wave * 8;
    unsigned short* aL0 = &As[wave * 1024];
    unsigned short* aL1 = &As[wave * 1024 + 512];
    unsigned short* gL  = &Gs[wave * 512];
    unsigned short* uL  = &Us[wave * 512];

    int kc = lane >> 4, mr = lane & 15;
    for (int k0 = 0; k0 < K; k0 += 32) {
        __syncthreads();
        gl_lds16(aG0 + k0, aL0);
        gl_lds16(aG1 + k0, aL1);
        gl_lds16(gG + k0, gL);
        gl_lds16(uG + k0, uL);
        __syncthreads();
        bf16x8 af[2], gf[4], uf[4];
        #pragma unroll
        for (int mi = 0; mi < 2; ++mi)
            af[mi] = *reinterpret_cast<const bf16x8*>(&As[kc * 1024 + (wave * 32 + mi * 16 + mr) * 8]);
        #pragma unroll
        for (int ni = 0; ni < 4; ++ni) {
            gf[ni] = *reinterpret_cast<const bf16x8*>(&Gs[kc * 512 + (ni * 16 + mr) * 8]);
            uf[ni] = *reinterpret_cast<const bf16x8*>(&Us[kc * 512 + (ni * 16 + mr) * 8]);
        }
        #pragma unroll
        for (int mi = 0; mi < 2; ++mi)
            #pragma unroll
            for (int ni = 0; ni < 4; ++ni) {
                accg[mi][ni] = __builtin_amdgcn_mfma_f32_16x16x32_bf16(af[mi], gf[ni], accg[mi][ni], 0, 0, 0);
                accu[mi][ni] = __builtin_amdgcn_mfma_f32_16x16x32_bf16(af[mi], uf[ni], accu[mi][ni], 0, 0, 0);
            }
    }
    int quad = lane >> 4;
    #pragma unroll
    for (int mi = 0; mi < 2; ++mi) {
        int rb = m0 + wave * 32 + mi * 16 + quad * 4;
        #pragma unroll
        for (int ni = 0; ni < 4; ++ni)
            #pragma unroll
            for (int r = 0; r < 4; ++r) {
                float g = accg[mi][ni][r];
                float gl = 0.5f * g * (1.f + tanhf(0.7978845608028654f * (g + 0.044715f * g * g * g)));
                float val = gl * accu[mi][ni][r];
                Cbf[(size_t)(rb + r) * N + n0 + ni * 16 + mr] = f2bf(val);
            }
    }
}

// ---------------- fused per-head LN + RoPE for q/k/v, bf16 out ------------------
// grid = ROWS_*12 ; hh: 0-7 = q heads, 8-9 = k heads, 10-11 = v heads (v transposed)
__global__ __launch_bounds__(256) void qkv_norm_rope_fused(
    const float* __restrict__ in, const float* __restrict__ qw,
    const float* __restrict__ kw,
    const float* __restrict__ cs, const float* __restrict__ sn,
    unsigned short* __restrict__ qo, unsigned short* __restrict__ ko,
    unsigned short* __restrict__ vo)
{
    int blk = blockIdx.x;
    int hh = blk % 12;
    int trow = blk / 12;
    int b = trow / T_;
    int t = trow % T_;
    int d = threadIdx.x;
    float x = in[(size_t)trow * 3072 + hh * HD_ + d];
    float mu = block_sum(x) * (1.f / HD_);
    float xc = x - mu;
    float var = block_sum(xc * xc) * (1.f / HD_);
    float wv_ = (hh < 8) ? qw[d] : (hh < 10 ? kw[d] : 1.f);
    float n = xc * rsqrtf(var + EPS_) * wv_;
    __shared__ float buf[HD_];
    buf[d] = n;
    __syncthreads();
    float val = n;
    if (hh < 10) {   // rope for q and k (block-uniform branch)
        float c = cs[(size_t)trow * HD_ + d];
        float s = sn[(size_t)trow * HD_ + d];
        float other = (d < 128) ? -buf[d + 128] : buf[d - 128];
        val = n * c + other * s;
    }
    if (hh < 8)
        qo[(((size_t)b * NH_ + hh) * T_ + t) * HD_ + d] = f2bf(val);
    else if (hh < 10)
        ko[(((size_t)b * NKV_ + (hh - 8)) * T_ + t) * HD_ + d] = f2bf(val);
    else
        vo[(((size_t)b * NKV_ + (hh - 10)) * HD_ + d) * T_ + t] = f2bf(val);
}

// ---------------- QK^T batched bf16 MFMA GEMM (causal tile-skip) ----------------
// Q: [16 heads][T,HD]; K: [4 kv][T,HD]; S: [8 heads of group][T,T] fp32
// grid (T/128, T/128, 8)
__global__ __launch_bounds__(256) void qk_gemm(
    const unsigned short* __restrict__ Q, const unsigned short* __restrict__ Kt,
    float* __restrict__ S, int head_base)
{
    if (blockIdx.x > blockIdx.y) return;   // tile fully above causal diagonal
    int z = blockIdx.z;
    int bh = head_base + z;
    const unsigned short* A  = Q  + (size_t)bh * T_ * HD_;
    const unsigned short* Bm = Kt + (size_t)(bh >> 2) * T_ * HD_;
    float* C = S + (size_t)z * T_ * T_;

    __shared__ unsigned short As[4096];
    __shared__ unsigned short Bs[4096];
    int tid = threadIdx.x;
    int lane = tid & 63;
    int wave = tid >> 6;
    int m0 = blockIdx.y * 128, n0 = blockIdx.x * 128;
    int wm = (wave >> 1) * 64;
    int wn = (wave & 1) * 64;
    floatx4 acc[4][4] = {};

    const unsigned short* aG0 = A  + (size_t)(m0 + lane)      * HD_ + wave * 8;
    const unsigned short* aG1 = A  + (size_t)(m0 + 64 + lane) * HD_ + wave * 8;
    const unsigned short* bG0 = Bm + (size_t)(n0 + lane)      * HD_ + wave * 8;
    const unsigned short* bG1 = Bm + (size_t)(n0 + 64 + lane) * HD_ + wave * 8;
    unsigned short* aL0 = &As[wave * 1024];
    unsigned short* aL1 = &As[wave * 1024 + 512];
    unsigned short* bL0 = &Bs[wave * 1024];
    unsigned short* bL1 = &Bs[wave * 1024 + 512];

    int kc = lane >> 4, mr = lane & 15;
    for (int k0 = 0; k0 < HD_; k0 += 32) {
        __syncthreads();
        gl_lds16(aG0 + k0, aL0);
        gl_lds16(aG1 + k0, aL1);
        gl_lds16(bG0 + k0, bL0);
        gl_lds16(bG1 + k0, bL1);
        __syncthreads();
        bf16x8 af[4], bfv[4];
        #pragma unroll
        for (int mi = 0; mi < 4; ++mi)
            af[mi] = *reinterpret_cast<const bf16x8*>(&As[kc * 1024 + (wm + mi * 16 + mr) * 8]);
        #pragma unroll
        for (int ni = 0; ni < 4; ++ni)
            bfv[ni] = *reinterpret_cast<const bf16x8*>(&Bs[kc * 1024 + (wn + ni * 16 + mr) * 8]);
        #pragma unroll
        for (int mi = 0; mi < 4; ++mi)
            #pragma unroll
            for (int ni = 0; ni < 4; ++ni)
                acc[mi][ni] = __builtin_amdgcn_mfma_f32_16x16x32_bf16(af[mi], bfv[ni], acc[mi][ni], 0, 0, 0);
    }
    int quad = lane >> 4;
    #pragma unroll
    for (int mi = 0; mi < 4; ++mi)
        #pragma unroll
        for (int ni = 0; ni < 4; ++ni)
            #pragma unroll
            for (int r = 0; r < 4; ++r)
                C[(size_t)(m0 + wm + mi * 16 + quad * 4 + r) * T_ + n0 + wn + ni * 16 + mr] = acc[mi][ni][r];
}

// ---------------- causal softmax: fp32 scores row -> bf16 probs row -------------
// grid (T, 8): x=query row, y=head-in-group. Writes zeros above diagonal.
__global__ __launch_bounds__(256) void softmax_causal(
    const float* __restrict__ S, unsigned short* __restrict__ P)
{
    int qi = blockIdx.x;
    int g  = blockIdx.y;
    int tid = threadIdx.x;
    int L = qi + 1;
    const float* Srow = S + ((size_t)g * T_ + qi) * T_;
    unsigned short* Prow = P + ((size_t)g * T_ + qi) * T_;
    float v[4];
    float mx = -3.402823466e38f;
    #pragma unroll
    for (int i = 0; i < 4; ++i) {
        int idx = i * 256 + tid;
        v[i] = (idx < L) ? Srow[idx] : -3.402823466e38f;
        mx = fmaxf(mx, v[i]);
    }
    mx = block_max(mx);
    float sm = 0.f;
    float e[4];
    #pragma unroll
    for (int i = 0; i < 4; ++i) {
        int idx = i * 256 + tid;
        e[i] = (idx < L) ? expf(v[i] - mx) : 0.f;
        sm += e[i];
    }
    sm = block_sum(sm);
    float inv = 1.f / sm;
    #pragma unroll
    for (int i = 0; i < 4; ++i)
        Prow[i * 256 + tid] = f2bf(e[i] * inv);
}

// ---------------- PV batched bf16 MFMA GEMM (causal K early-exit) ---------------
// P: [16][T,T] bf16; Vt: [4 kv][HD,T] bf16; out bf16 [B*T, NH*HD]
// grid (HD/128=2, T/128=8, 16)
__global__ __launch_bounds__(256) void pv_gemm(
    const unsigned short* __restrict__ P, const unsigned short* __restrict__ Vt,
    unsigned short* __restrict__ Out)
{
    int z = blockIdx.z;
    int b = z >> 3;
    int h = z & 7;
    const unsigned short* A  = P  + (size_t)z * T_ * T_;
    const unsigned short* Bm = Vt + (size_t)(z >> 2) * HD_ * T_;

    __shared__ unsigned short As[4096];
    __shared__ unsigned short Bs[4096];
    int tid = threadIdx.x;
    int lane = tid & 63;
    int wave = tid >> 6;
    int m0 = blockIdx.y * 128, n0 = blockIdx.x * 128;
    int Kend = m0 + 128;      // rows in this tile only attend keys < m0+128
    int wm = (wave >> 1) * 64;
    int wn = (wave & 1) * 64;
    floatx4 acc[4][4] = {};

    const unsigned short* aG0 = A  + (size_t)(m0 + lane)      * T_ + wave * 8;
    const unsigned short* aG1 = A  + (size_t)(m0 + 64 + lane) * T_ + wave * 8;
    const unsigned short* bG0 = Bm + (size_t)(n0 + lane)      * T_ + wave * 8;
    const unsigned short* bG1 = Bm + (size_t)(n0 + 64 + lane) * T_ + wave * 8;
    unsigned short* aL0 = &As[wave * 1024];
    unsigned short* aL1 = &As[wave * 1024 + 512];
    unsigned short* bL0 = &Bs[wave * 1024];
    unsigned short* bL1 = &Bs[wave * 1024 + 512];

    int kc = lane >> 4, mr = lane & 15;
    for (int k0 = 0; k0 < Kend; k0 += 32) {
        __syncthreads();
        gl_lds16(aG0 + k0, aL0);
        gl_lds16(aG1 + k0, aL1);
        gl_lds16(bG0 + k0, bL0);
        gl_lds16(bG1 + k0, bL1);
        __syncthreads();
        bf16x8 af[4], bfv[4];
        #pragma unroll
        for (int mi = 0; mi < 4; ++mi)
            af[mi] = *reinterpret_cast<const bf16x8*>(&As[kc * 1024 + (wm + mi * 16 + mr) * 8]);
        #pragma unroll
        for (int ni = 0; ni < 4; ++ni)
            bfv[ni] = *reinterpret_cast<const bf16x8*>(&Bs[kc * 1024 + (wn + ni * 16 + mr) * 8]);
        #pragma unroll
        for (int mi = 0; mi < 4; ++mi)
            #pragma unroll
            for (int ni = 0; ni < 4; ++ni)
                acc[mi][ni] = __builtin_amdgcn_mfma_f32_16x16x32_bf16(af[mi], bfv[ni], acc[mi][ni], 0, 0, 0);
    }
    int quad = lane >> 4;
    #pragma unroll
    for (int mi = 0; mi < 4; ++mi)
        #pragma unroll
        for (int ni = 0; ni < 4; ++ni)
            #pragma unroll
            for (int r = 0; r < 4; ++r) {
                int row = m0 + wm + mi * 16 + quad * 4 + r;
                int col = n0 + wn + ni * 16 + mr;
                Out[((size_t)(b * T_ + row)) * (NH_ * HD_) + h * HD_ + col] =
                    f2bf(acc[mi][ni][r]);
            }
}

// ---------------- altup correct + output-scale on stream 0 ----------------------
__global__ __launch_bounds__(256) void correct_kernel(
    const float* __restrict__ act, const float* __restrict__ pred,
    const float* __restrict__ mc, const float* __restrict__ ccw,
    const float* __restrict__ cscale, float* __restrict__ out)
{
    size_t row = blockIdx.x;
    int tid = threadIdx.x;
    __shared__ float ms[4];
    __shared__ float cc[4];
    if (tid < 4) ms[tid] = mc[row * S_ + tid];
    __syncthreads();
    if (tid < 4) {
        float s = 1.f;
        #pragma unroll
        for (int i = 0; i < 4; ++i) s += ms[i] * ccw[tid * 4 + i];
        cc[tid] = s;
    }
    __syncthreads();
    const size_t STRIDE = (size_t)ROWS_ * H_;
    #pragma unroll
    for (int i = 0; i < 8; ++i) {
        size_t idx = row * H_ + i*256 + tid;
        float a  = act[idx];
        float p0 = pred[idx];
        float inn = a - p0;
        #pragma unroll
        for (int j = 0; j < 4; ++j) {
            float val = inn * cc[j] + pred[idx + (size_t)j * STRIDE];
            if (j == 0) val *= cscale[i*256 + tid];
            out[idx + (size_t)j * STRIDE] = val;
        }
    }
}

// ---------------- launcher ----------------
extern "C" void kernel_launch(void* const* d_in, const int* in_sizes, int n_in,
                              void* d_out, int out_size, void* d_ws, size_t ws_size,
                              hipStream_t stream)
{
    (void)in_sizes; (void)n_in; (void)out_size; (void)ws_size;
    const float* hidden         = (const float*)d_in[0];
    const float* cosp           = (const float*)d_in[1];
    const float* sinp           = (const float*)d_in[2];
    const float* wq             = (const float*)d_in[3];
    const float* wk             = (const float*)d_in[4];
    const float* wv             = (const float*)d_in[5];
    const float* wo             = (const float*)d_in[6];
    const float* q_norm_w       = (const float*)d_in[7];
    const float* k_norm_w       = (const float*)d_in[8];
    const float* input_ln_w     = (const float*)d_in[9];
    const float* post_attn_ln_w = (const float*)d_in[10];
    const float* pre_ffw_ln_w   = (const float*)d_in[11];
    const float* post_ffw_ln_w  = (const float*)d_in[12];
    const float* gate_w         = (const float*)d_in[13];
    const float* up_w           = (const float*)d_in[14];
    const float* down_w         = (const float*)d_in[15];
    const float* ll_w           = (const float*)d_in[16];
    const float* lr_w           = (const float*)d_in[17];
    const float* laurel_norm_w  = (const float*)d_in[18];
    const float* router_norm_w  = (const float*)d_in[19];
    const float* router_w       = (const float*)d_in[20];
    const float* pred_coef_w    = (const float*)d_in[21];
    const float* corr_coef_w    = (const float*)d_in[22];
    const float* cscale         = (const float*)d_in[23];
    float* outp = (float*)d_out;

    char* base = (char*)d_ws;
    float* pred   = (float*)base;              base += 67108864;   // [4,R,H] fp32
    float* xnorm  = (float*)base;              base += 16777216;   // also split-K partial
    unsigned short* xnorm_bf = (unsigned short*)base; base += 8388608;
    float* lout   = (float*)base;              base += 16777216;
    float* alaur  = (float*)base;              base += 16777216;
    float* tmpH   = (float*)base;              base += 16777216;
    float* mbuf   = (float*)base;              base += 32768;
    float* mcbuf  = (float*)base;              base += 32768;
    float* ltmp   = (float*)base;              base += 524288;
    char* arena = base;                        // 100,663,296 B
    // attention phase layout
    unsigned short* qkvw_bf = (unsigned short*)arena;                 // 12,582,912 B
    float* qkv_pre = (float*)(arena + 12582912);                      // 25,165,824 B (dead after rope)
    unsigned short* Pbuf    = (unsigned short*)arena;                 // 33,554,432 B (16 heads bf16, over dead qkvw/qkv_pre)
    unsigned short* q_bf    = (unsigned short*)(arena + 37748736);    //  8,388,608 B
    unsigned short* k_bf    = (unsigned short*)(arena + 46137344);    //  2,097,152 B
    unsigned short* vT_bf   = (unsigned short*)(arena + 48234496);    //  2,097,152 B
    unsigned short* attn_bf = (unsigned short*)(arena + 50331648);    //  8,388,608 B
    unsigned short* wo_bf   = (unsigned short*)(arena + 58720256);    //  8,388,608 B
    float* Sbuf             = (float*)(arena + 67108864);             // 33,554,432 B (8 heads fp32)
    // MLP phase layout (aliases attention phase)
    unsigned short* gate_bf = (unsigned short*)arena;
    unsigned short* up_bf   = (unsigned short*)(arena + 33554432);
    unsigned short* gu_bf   = (unsigned short*)(arena + 67108864);
    unsigned short* down_bf = gate_bf;
    float* activated = lout;

    // ---- AltUp predict ----
    router_kernel <<<ROWS_, 256, 0, stream>>>(hidden, router_norm_w, router_w, mbuf);
    predict_kernel<<<ROWS_, 256, 0, stream>>>(hidden, mbuf, pred_coef_w, pred);
    ln_residual   <<<ROWS_, 256, 0, stream>>>(pred, nullptr, input_ln_w, nullptr, nullptr, 1.f, xnorm, xnorm_bf);

    // ---- Laurel (fp32, small) ----
    gemm_nt<<<dim3(LR_/BN, ROWS_/BM), 256, 0, stream>>>(xnorm, ll_w, ltmp, ROWS_, LR_, H_);
    gemm_nt<<<dim3(H_/BN,  ROWS_/BM), 256, 0, stream>>>(ltmp, lr_w, tmpH, ROWS_, H_, LR_);
    ln_residual<<<ROWS_, 256, 0, stream>>>(tmpH, nullptr, laurel_norm_w, xnorm, nullptr, 1.f, lout, nullptr);

    // ---- Attention ----
    cvt_bf16<<<2048, 256, 0, stream>>>(wq, qkvw_bf,            4194304);
    cvt_bf16<<< 512, 256, 0, stream>>>(wk, qkvw_bf + 4194304,  1048576);
    cvt_bf16<<< 512, 256, 0, stream>>>(wv, qkvw_bf + 5242880,  1048576);
    gemm_bf16nt<<<dim3(24, 16, 1), 256, 0, stream>>>(xnorm_bf, qkvw_bf, qkv_pre, nullptr, ROWS_, 3072, H_);
    qkv_norm_rope_fused<<<ROWS_*12, 256, 0, stream>>>(qkv_pre, q_norm_w, k_norm_w, cosp, sinp, q_bf, k_bf, vT_bf);
    cvt_bf16<<<2048, 256, 0, stream>>>(wo, wo_bf, 4194304);
    for (int hb = 0; hb < B_ * NH_; hb += 8) {
        qk_gemm       <<<dim3(8, 8, 8), 256, 0, stream>>>(q_bf, k_bf, Sbuf, hb);
        softmax_causal<<<dim3(T_, 8),   256, 0, stream>>>(Sbuf, Pbuf + (size_t)hb * T_ * T_);
    }
    pv_gemm<<<dim3(2, 8, 16), 256, 0, stream>>>(Pbuf, vT_bf, attn_bf);
    gemm_bf16nt<<<dim3(16, 16, 2), 256, 0, stream>>>(attn_bf, wo_bf, tmpH, xnorm, ROWS_, H_, NH_*HD_);
    ln_residual<<<ROWS_, 256, 0, stream>>>(tmpH, xnorm, post_attn_ln_w, pred, lout, 0.7071067811865475f, alaur, nullptr);

    // ---- MLP ----
    ln_residual<<<ROWS_, 256, 0, stream>>>(alaur, nullptr, pre_ffw_ln_w, nullptr, nullptr, 1.f, nullptr, xnorm_bf);
    cvt_bf16<<<8192, 256, 0, stream>>>(gate_w, gate_bf, 16777216);
    cvt_bf16<<<8192, 256, 0, stream>>>(up_w,   up_bf,   16777216);
    gemm_gateup_bf16<<<dim3(128, 16), 256, 0, stream>>>(xnorm_bf, gate_bf, up_bf, gu_bf, ROWS_, FF_, H_);
    cvt_bf16<<<8192, 256, 0, stream>>>(down_w, down_bf, 16777216);
    gemm_bf16nt<<<dim3(16, 16, 2), 256, 0, stream>>>(gu_bf, down_bf, tmpH, xnorm, ROWS_, H_, FF_);
    ln_residual<<<ROWS_, 256, 0, stream>>>(tmpH, xnorm, post_ffw_ln_w, alaur, nullptr, 1.f, activated, nullptr);

    // ---- AltUp correct ----
    router_kernel <<<ROWS_, 256, 0, stream>>>(activated, router_norm_w, router_w, mcbuf);
    correct_kernel<<<ROWS_, 256, 0, stream>>>(activated, pred, mcbuf, corr_coef_w, cscale, outp);
}

// Round 3
// 1182.927 us; speedup vs baseline: 1.0163x; 1.0163x over previous
//
#include <hip/hip_runtime.h>
#include <hip/hip_bf16.h>
#include <math.h>

#define B_   2
#define T_   1024
#define H_   2048
#define NH_  8
#define NKV_ 2
#define HD_  256
#define S_   4
#define FF_  8192
#define LR_  64
#define ROWS_ (B_*T_)          // 2048 tokens
#define EPS_ 1e-6f

typedef __attribute__((ext_vector_type(8))) __bf16 bf16x8;
typedef __attribute__((ext_vector_type(4))) float floatx4;
typedef __attribute__((ext_vector_type(8))) unsigned short ushort8v;

__device__ __forceinline__ unsigned short f2bf(float f) {
    unsigned int u = __float_as_uint(f);
    return (unsigned short)((u + 0x7FFFu + ((u >> 16) & 1u)) >> 16);
}

// async global->LDS, 16B per lane. LDS dest is wave-uniform base + lane*16.
__device__ __forceinline__ void gl_lds16(const void* g, void* l) {
    __builtin_amdgcn_global_load_lds(
        (const __attribute__((address_space(1))) void*)g,
        (__attribute__((address_space(3))) void*)l, 16, 0, 0);
}

// ---------------- block-wide reductions (256 threads = 4 waves) ----------------
__device__ __forceinline__ float block_sum(float v) {
    __shared__ float s4[4];
    #pragma unroll
    for (int o = 32; o > 0; o >>= 1) v += __shfl_down(v, o, 64);
    int lane = threadIdx.x & 63;
    int w    = threadIdx.x >> 6;
    __syncthreads();
    if (lane == 0) s4[w] = v;
    __syncthreads();
    return s4[0] + s4[1] + s4[2] + s4[3];
}

__device__ __forceinline__ float block_max(float v) {
    __shared__ float s4m[4];
    #pragma unroll
    for (int o = 32; o > 0; o >>= 1) v = fmaxf(v, __shfl_down(v, o, 64));
    int lane = threadIdx.x & 63;
    int w    = threadIdx.x >> 6;
    __syncthreads();
    if (lane == 0) s4m[w] = v;
    __syncthreads();
    return fmaxf(fmaxf(s4m[0], s4m[1]), fmaxf(s4m[2], s4m[3]));
}

// ---------------- fp32 -> bf16 convert (8 elements/thread) ----------------------
__global__ __launch_bounds__(256) void cvt_bf16(
    const float* __restrict__ in, unsigned short* __restrict__ out, int n)
{
    int i = (blockIdx.x * 256 + threadIdx.x) * 8;
    if (i >= n) return;
    float4 v0 = *reinterpret_cast<const float4*>(in + i);
    float4 v1 = *reinterpret_cast<const float4*>(in + i + 4);
    ushort8v o;
    o[0] = f2bf(v0.x); o[1] = f2bf(v0.y); o[2] = f2bf(v0.z); o[3] = f2bf(v0.w);
    o[4] = f2bf(v1.x); o[5] = f2bf(v1.y); o[6] = f2bf(v1.z); o[7] = f2bf(v1.w);
    *reinterpret_cast<ushort8v*>(out + i) = o;
}

// ---------------- router: m = tanh( (LN(x)*w_norm / H) @ router_w^T ) ----------
__global__ __launch_bounds__(256) void router_kernel(
    const float* __restrict__ x, const float* __restrict__ nw,
    const float* __restrict__ rw, float* __restrict__ mout)
{
    size_t row = blockIdx.x;
    int tid = threadIdx.x;
    const float* xr = x + row * H_;
    float v[8]; float s = 0.f;
    #pragma unroll
    for (int i = 0; i < 8; ++i) { v[i] = xr[i*256 + tid]; s += v[i]; }
    float mu = block_sum(s) * (1.f / H_);
    float ss = 0.f;
    #pragma unroll
    for (int i = 0; i < 8; ++i) { float c = v[i] - mu; ss += c * c; }
    float rstd = rsqrtf(block_sum(ss) * (1.f / H_) + EPS_);
    float n[8];
    #pragma unroll
    for (int i = 0; i < 8; ++i) n[i] = (v[i] - mu) * rstd * nw[i*256 + tid];
    for (int so = 0; so < S_; ++so) {
        float p = 0.f;
        #pragma unroll
        for (int i = 0; i < 8; ++i) p += n[i] * rw[(size_t)so * H_ + i*256 + tid];
        float dot = block_sum(p);
        if (tid == 0) mout[row * S_ + so] = tanhf(dot * (1.f / H_));
    }
}

// ---------------- altup predict ----------------
__global__ __launch_bounds__(256) void predict_kernel(
    const float* __restrict__ hid, const float* __restrict__ m,
    const float* __restrict__ pcw, float* __restrict__ pred)
{
    size_t row = blockIdx.x;
    int tid = threadIdx.x;
    __shared__ float ms[4];
    __shared__ float c[16];
    if (tid < 4) ms[tid] = m[row * S_ + tid];
    __syncthreads();
    if (tid < 16) {
        float s = 0.f;
        #pragma unroll
        for (int i = 0; i < 4; ++i) s += ms[i] * pcw[tid * 4 + i];
        c[tid] = s;
    }
    __syncthreads();
    const size_t STRIDE = (size_t)ROWS_ * H_;
    #pragma unroll
    for (int i = 0; i < 8; ++i) {
        size_t idx = row * H_ + i*256 + tid;
        float h0 = hid[idx];
        float h1 = hid[idx + STRIDE];
        float h2 = hid[idx + 2*STRIDE];
        float h3 = hid[idx + 3*STRIDE];
        float hv[4] = {h0, h1, h2, h3};
        #pragma unroll
        for (int j = 0; j < 4; ++j) {
            float val = hv[j] + h0*c[j*4+0] + h1*c[j*4+1] + h2*c[j*4+2] + h3*c[j*4+3];
            pred[idx + (size_t)j * STRIDE] = val;
        }
    }
}

// ---- LN (+ optional pre-add xadd, residuals a1/a2, scale, fp32/bf16 out) -------
__global__ __launch_bounds__(256) void ln_residual(
    const float* __restrict__ x, const float* __restrict__ xadd,
    const float* __restrict__ w,
    const float* __restrict__ a1, const float* __restrict__ a2,
    float scale, float* __restrict__ out, unsigned short* __restrict__ outb)
{
    size_t row = blockIdx.x;
    int tid = threadIdx.x;
    const float* xr = x + row * H_;
    const float* xa = xadd ? xadd + row * H_ : nullptr;
    float v[8]; float s = 0.f;
    #pragma unroll
    for (int i = 0; i < 8; ++i) {
        v[i] = xr[i*256 + tid];
        if (xa) v[i] += xa[i*256 + tid];
        s += v[i];
    }
    float mu = block_sum(s) * (1.f / H_);
    float ss = 0.f;
    #pragma unroll
    for (int i = 0; i < 8; ++i) { float c = v[i] - mu; ss += c * c; }
    float rstd = rsqrtf(block_sum(ss) * (1.f / H_) + EPS_);
    #pragma unroll
    for (int i = 0; i < 8; ++i) {
        size_t idx = row * H_ + i*256 + tid;
        float y = (v[i] - mu) * rstd * w[i*256 + tid];
        if (a1) y += a1[idx];
        if (a2) y += a2[idx];
        y *= scale;
        if (out)  out[idx]  = y;
        if (outb) outb[idx] = f2bf(y);
    }
}

// ---------------- fp32 GEMM (laurel only): C = A[M,K] * B[N,K]^T ----------------
#define BM 64
#define BN 64
#define BK 32
#define LDP 68

__global__ __launch_bounds__(256) void gemm_nt(
    const float* __restrict__ A, const float* __restrict__ Bm,
    float* __restrict__ C, int M, int N, int K)
{
    __shared__ float As[BK][LDP];
    __shared__ float Bs[BK][LDP];
    int tid = threadIdx.x;
    int n0 = blockIdx.x * BN;
    int m0 = blockIdx.y * BM;
    int tx = tid & 15, ty = tid >> 4;
    int lrow = tid >> 3;
    int lk   = (tid & 7) << 2;
    float acc[4][4] = {};
    for (int k0 = 0; k0 < K; k0 += BK) {
        #pragma unroll
        for (int r = 0; r < 2; ++r) {
            int row = lrow + r * 32;
            float4 a4 = *reinterpret_cast<const float4*>(&A[(size_t)(m0 + row) * K + k0 + lk]);
            As[lk+0][row] = a4.x; As[lk+1][row] = a4.y; As[lk+2][row] = a4.z; As[lk+3][row] = a4.w;
            float4 b4 = *reinterpret_cast<const float4*>(&Bm[(size_t)(n0 + row) * K + k0 + lk]);
            Bs[lk+0][row] = b4.x; Bs[lk+1][row] = b4.y; Bs[lk+2][row] = b4.z; Bs[lk+3][row] = b4.w;
        }
        __syncthreads();
        #pragma unroll
        for (int k = 0; k < BK; ++k) {
            float4 av = *reinterpret_cast<const float4*>(&As[k][ty << 2]);
            float4 bv = *reinterpret_cast<const float4*>(&Bs[k][tx << 2]);
            float a[4] = {av.x, av.y, av.z, av.w};
            float b[4] = {bv.x, bv.y, bv.z, bv.w};
            #pragma unroll
            for (int i = 0; i < 4; ++i)
                #pragma unroll
                for (int j = 0; j < 4; ++j)
                    acc[i][j] = fmaf(a[i], b[j], acc[i][j]);
        }
        __syncthreads();
    }
    #pragma unroll
    for (int i = 0; i < 4; ++i) {
        float4 o; o.x = acc[i][0]; o.y = acc[i][1]; o.z = acc[i][2]; o.w = acc[i][3];
        *reinterpret_cast<float4*>(&C[(size_t)(m0 + (ty << 2) + i) * N + n0 + (tx << 2)]) = o;
    }
}

// ---------------- bf16 MFMA GEMM, gl_lds + explicit LDS double-buffer -----------
// C[M,N] (fp32) = A_bf16[M,K] * B_bf16[N,K]^T.  128x128 tile, BK=32.
// 2-phase: prefetch tile k+1 into buf^1 BEFORE computing buf (T3 minimum recipe).
// grid.z = split-K: z==0 -> C, z==1 -> C2 (consumer sums).
__global__ __launch_bounds__(256) void gemm_bf16nt(
    const unsigned short* __restrict__ A, const unsigned short* __restrict__ Bm,
    float* __restrict__ C, float* __restrict__ C2, int M, int N, int K)
{
    __shared__ unsigned short As[8192];   // [buf:2][kc:4][m:128][8]
    __shared__ unsigned short Bs[8192];
    int tid = threadIdx.x;
    int lane = tid & 63;
    int wave = tid >> 6;
    int m0 = blockIdx.y * 128, n0 = blockIdx.x * 128;
    int Kper = K / gridDim.z;
    int kbeg = blockIdx.z * Kper;
    int kend = kbeg + Kper;
    int wm = (wave >> 1) * 64;
    int wn = (wave & 1) * 64;
    floatx4 acc[4][4] = {};

    // staging: wave w owns k-chunk w (8 shorts), lanes map to rows
    const unsigned short* aG0 = A  + (size_t)(m0 + lane)      * K + wave * 8;
    const unsigned short* aG1 = A  + (size_t)(m0 + 64 + lane) * K + wave * 8;
    const unsigned short* bG0 = Bm + (size_t)(n0 + lane)      * K + wave * 8;
    const unsigned short* bG1 = Bm + (size_t)(n0 + 64 + lane) * K + wave * 8;

    int kc = lane >> 4, mr = lane & 15;

    // prologue: stage first tile into buf 0
    {
        unsigned short* a = &As[wave * 1024];
        unsigned short* b = &Bs[wave * 1024];
        gl_lds16(aG0 + kbeg, a);
        gl_lds16(aG1 + kbeg, a + 512);
        gl_lds16(bG0 + kbeg, b);
        gl_lds16(bG1 + kbeg, b + 512);
    }
    __syncthreads();
    int cur = 0;
    for (int k0 = kbeg; k0 < kend; k0 += 32) {
        if (k0 + 32 < kend) {           // issue next-tile prefetch FIRST
            int nb = (cur ^ 1) * 4096;
            unsigned short* a = &As[nb + wave * 1024];
            unsigned short* b = &Bs[nb + wave * 1024];
            gl_lds16(aG0 + k0 + 32, a);
            gl_lds16(aG1 + k0 + 32, a + 512);
            gl_lds16(bG0 + k0 + 32, b);
            gl_lds16(bG1 + k0 + 32, b + 512);
        }
        int cb = cur * 4096;
        bf16x8 af[4], bfv[4];
        #pragma unroll
        for (int mi = 0; mi < 4; ++mi)
            af[mi] = *reinterpret_cast<const bf16x8*>(&As[cb + kc * 1024 + (wm + mi * 16 + mr) * 8]);
        #pragma unroll
        for (int ni = 0; ni < 4; ++ni)
            bfv[ni] = *reinterpret_cast<const bf16x8*>(&Bs[cb + kc * 1024 + (wn + ni * 16 + mr) * 8]);
        #pragma unroll
        for (int mi = 0; mi < 4; ++mi)
            #pragma unroll
            for (int ni = 0; ni < 4; ++ni)
                acc[mi][ni] = __builtin_amdgcn_mfma_f32_16x16x32_bf16(af[mi], bfv[ni], acc[mi][ni], 0, 0, 0);
        __syncthreads();   // drains prefetch vmcnt + fences reads of cur
        cur ^= 1;
    }
    float* Cout = (blockIdx.z == 0) ? C : C2;
    int quad = lane >> 4;
    #pragma unroll
    for (int mi = 0; mi < 4; ++mi)
        #pragma unroll
        for (int ni = 0; ni < 4; ++ni)
            #pragma unroll
            for (int r = 0; r < 4; ++r)
                Cout[(size_t)(m0 + wm + mi * 16 + quad * 4 + r) * N + n0 + wn + ni * 16 + mr] = acc[mi][ni][r];
}

// ---------------- fused gate/up bf16 GEMM -> gu_bf16 = gelu(A*G^T)*(A*U^T) ------
// BM=128, BN=64, BK=32; gl_lds + dbuf prefetch; 4 waves each 32 rows x 64 cols
__global__ __launch_bounds__(256) void gemm_gateup_bf16(
    const unsigned short* __restrict__ A, const unsigned short* __restrict__ G,
    const unsigned short* __restrict__ U, unsigned short* __restrict__ Cbf,
    int M, int N, int K)
{
    __shared__ unsigned short As[8192];  // [buf:2][kc:4][m:128][8]
    __shared__ unsigned short Gs[4096];  // [buf:2][kc:4][n:64][8]
    __shared__ unsigned short Us[4096];
    int tid = threadIdx.x;
    int lane = tid & 63;
    int wave = tid >> 6;
    int m0 = blockIdx.y * 128, n0 = blockIdx.x * 64;
    floatx4 accg[2][4] = {};
    floatx4 accu[2][4] = {};

    const unsigned short* aG0 = A + (size_t)(m0 + lane)      * K + wave * 8;
    const unsigned short* aG1 = A + (size_t)(m0 + 64 + lane) * K + wave * 8;
    const unsigned short* gG  = G + (size_t)(n0 + lane)      * K + wave * 8;
    const unsigned short* uG  = U + (size_t)(n0 + lane)      * K + wave * 8;

    int kc = lane >> 4, mr = lane & 15;

    {
        gl_lds16(aG0, &As[wave * 1024]);
        gl_lds16(aG1, &As[wave * 1024 + 512]);
        gl_lds16(gG,  &Gs[wave * 512]);
        gl_lds16(uG,  &Us[wave * 512]);
    }
    __syncthreads();
    int cur = 0;
    for (int k0 = 0; k0 < K; k0 += 32) {
        if (k0 + 32 < K) {
            int a_nb = (cur ^ 1) * 4096;
            int g_nb = (cur ^ 1) * 2048;
            gl_lds16(aG0 + k0 + 32, &As[a_nb + wave * 1024]);
            gl_lds16(aG1 + k0 + 32, &As[a_nb + wave * 1024 + 512]);
            gl_lds16(gG + k0 + 32,  &Gs[g_nb + wave * 512]);
            gl_lds16(uG + k0 + 32,  &Us[g_nb + wave * 512]);
        }
        int ab = cur * 4096, gb = cur * 2048;
        bf16x8 af[2], gf[4], uf[4];
        #pragma unroll
        for (int mi = 0; mi < 2; ++mi)
            af[mi] = *reinterpret_cast<const bf16x8*>(&As[ab + kc * 1024 + (wave * 32 + mi * 16 + mr) * 8]);
        #pragma unroll
        for (int ni = 0; ni < 4; ++ni) {
            gf[ni] = *reinterpret_cast<const bf16x8*>(&Gs[gb + kc * 512 + (ni * 16 + mr) * 8]);
            uf[ni] = *reinterpret_cast<const bf16x8*>(&Us[gb + kc * 512 + (ni * 16 + mr) * 8]);
        }
        #pragma unroll
        for (int mi = 0; mi < 2; ++mi)
            #pragma unroll
            for (int ni = 0; ni < 4; ++ni) {
                accg[mi][ni] = __builtin_amdgcn_mfma_f32_16x16x32_bf16(af[mi], gf[ni], accg[mi][ni], 0, 0, 0);
                accu[mi][ni] = __builtin_amdgcn_mfma_f32_16x16x32_bf16(af[mi], uf[ni], accu[mi][ni], 0, 0, 0);
            }
        __syncthreads();
        cur ^= 1;
    }
    int quad = lane >> 4;
    #pragma unroll
    for (int mi = 0; mi < 2; ++mi) {
        int rb = m0 + wave * 32 + mi * 16 + quad * 4;
        #pragma unroll
        for (int ni = 0; ni < 4; ++ni)
            #pragma unroll
            for (int r = 0; r < 4; ++r) {
                float g = accg[mi][ni][r];
                float gl = 0.5f * g * (1.f + tanhf(0.7978845608028654f * (g + 0.044715f * g * g * g)));
                float val = gl * accu[mi][ni][r];
                Cbf[(size_t)(rb + r) * N + n0 + ni * 16 + mr] = f2bf(val);
            }
    }
}

// ---------------- fused per-head LN + RoPE for q/k/v, bf16 out ------------------
// grid = ROWS_*12 ; hh: 0-7 = q heads, 8-9 = k heads, 10-11 = v heads (v transposed)
__global__ __launch_bounds__(256) void qkv_norm_rope_fused(
    const float* __restrict__ in, const float* __restrict__ qw,
    const float* __restrict__ kw,
    const float* __restrict__ cs, const float* __restrict__ sn,
    unsigned short* __restrict__ qo, unsigned short* __restrict__ ko,
    unsigned short* __restrict__ vo)
{
    int blk = blockIdx.x;
    int hh = blk % 12;
    int trow = blk / 12;
    int b = trow / T_;
    int t = trow % T_;
    int d = threadIdx.x;
    float x = in[(size_t)trow * 3072 + hh * HD_ + d];
    float mu = block_sum(x) * (1.f / HD_);
    float xc = x - mu;
    float var = block_sum(xc * xc) * (1.f / HD_);
    float wv_ = (hh < 8) ? qw[d] : (hh < 10 ? kw[d] : 1.f);
    float n = xc * rsqrtf(var + EPS_) * wv_;
    __shared__ float buf[HD_];
    buf[d] = n;
    __syncthreads();
    float val = n;
    if (hh < 10) {   // rope for q and k (block-uniform branch)
        float c = cs[(size_t)trow * HD_ + d];
        float s = sn[(size_t)trow * HD_ + d];
        float other = (d < 128) ? -buf[d + 128] : buf[d - 128];
        val = n * c + other * s;
    }
    if (hh < 8)
        qo[(((size_t)b * NH_ + hh) * T_ + t) * HD_ + d] = f2bf(val);
    else if (hh < 10)
        ko[(((size_t)b * NKV_ + (hh - 8)) * T_ + t) * HD_ + d] = f2bf(val);
    else
        vo[(((size_t)b * NKV_ + (hh - 10)) * HD_ + d) * T_ + t] = f2bf(val);
}

// ---------------- QK^T batched bf16 MFMA GEMM (causal tile-skip, dbuf) ----------
// Q: [16 heads][T,HD]; K: [4 kv][T,HD]; S: [8 heads of group][T,T] fp32
// grid (T/128, T/128, 8)
__global__ __launch_bounds__(256) void qk_gemm(
    const unsigned short* __restrict__ Q, const unsigned short* __restrict__ Kt,
    float* __restrict__ S, int head_base)
{
    if (blockIdx.x > blockIdx.y) return;   // tile fully above causal diagonal
    int z = blockIdx.z;
    int bh = head_base + z;
    const unsigned short* A  = Q  + (size_t)bh * T_ * HD_;
    const unsigned short* Bm = Kt + (size_t)(bh >> 2) * T_ * HD_;
    float* C = S + (size_t)z * T_ * T_;

    __shared__ unsigned short As[8192];
    __shared__ unsigned short Bs[8192];
    int tid = threadIdx.x;
    int lane = tid & 63;
    int wave = tid >> 6;
    int m0 = blockIdx.y * 128, n0 = blockIdx.x * 128;
    int wm = (wave >> 1) * 64;
    int wn = (wave & 1) * 64;
    floatx4 acc[4][4] = {};

    const unsigned short* aG0 = A  + (size_t)(m0 + lane)      * HD_ + wave * 8;
    const unsigned short* aG1 = A  + (size_t)(m0 + 64 + lane) * HD_ + wave * 8;
    const unsigned short* bG0 = Bm + (size_t)(n0 + lane)      * HD_ + wave * 8;
    const unsigned short* bG1 = Bm + (size_t)(n0 + 64 + lane) * HD_ + wave * 8;

    int kc = lane >> 4, mr = lane & 15;

    {
        gl_lds16(aG0, &As[wave * 1024]);
        gl_lds16(aG1, &As[wave * 1024 + 512]);
        gl_lds16(bG0, &Bs[wave * 1024]);
        gl_lds16(bG1, &Bs[wave * 1024 + 512]);
    }
    __syncthreads();
    int cur = 0;
    for (int k0 = 0; k0 < HD_; k0 += 32) {
        if (k0 + 32 < HD_) {
            int nb = (cur ^ 1) * 4096;
            gl_lds16(aG0 + k0 + 32, &As[nb + wave * 1024]);
            gl_lds16(aG1 + k0 + 32, &As[nb + wave * 1024 + 512]);
            gl_lds16(bG0 + k0 + 32, &Bs[nb + wave * 1024]);
            gl_lds16(bG1 + k0 + 32, &Bs[nb + wave * 1024 + 512]);
        }
        int cb = cur * 4096;
        bf16x8 af[4], bfv[4];
        #pragma unroll
        for (int mi = 0; mi < 4; ++mi)
            af[mi] = *reinterpret_cast<const bf16x8*>(&As[cb + kc * 1024 + (wm + mi * 16 + mr) * 8]);
        #pragma unroll
        for (int ni = 0; ni < 4; ++ni)
            bfv[ni] = *reinterpret_cast<const bf16x8*>(&Bs[cb + kc * 1024 + (wn + ni * 16 + mr) * 8]);
        #pragma unroll
        for (int mi = 0; mi < 4; ++mi)
            #pragma unroll
            for (int ni = 0; ni < 4; ++ni)
                acc[mi][ni] = __builtin_amdgcn_mfma_f32_16x16x32_bf16(af[mi], bfv[ni], acc[mi][ni], 0, 0, 0);
        __syncthreads();
        cur ^= 1;
    }
    int quad = lane >> 4;
    #pragma unroll
    for (int mi = 0; mi < 4; ++mi)
        #pragma unroll
        for (int ni = 0; ni < 4; ++ni)
            #pragma unroll
            for (int r = 0; r < 4; ++r)
                C[(size_t)(m0 + wm + mi * 16 + quad * 4 + r) * T_ + n0 + wn + ni * 16 + mr] = acc[mi][ni][r];
}

// ---------------- causal softmax: fp32 scores row -> bf16 probs row -------------
// grid (T, 8): x=query row, y=head-in-group. Writes zeros above diagonal.
__global__ __launch_bounds__(256) void softmax_causal(
    const float* __restrict__ S, unsigned short* __restrict__ P)
{
    int qi = blockIdx.x;
    int g  = blockIdx.y;
    int tid = threadIdx.x;
    int L = qi + 1;
    const float* Srow = S + ((size_t)g * T_ + qi) * T_;
    unsigned short* Prow = P + ((size_t)g * T_ + qi) * T_;
    float v[4];
    float mx = -3.402823466e38f;
    #pragma unroll
    for (int i = 0; i < 4; ++i) {
        int idx = i * 256 + tid;
        v[i] = (idx < L) ? Srow[idx] : -3.402823466e38f;
        mx = fmaxf(mx, v[i]);
    }
    mx = block_max(mx);
    float sm = 0.f;
    float e[4];
    #pragma unroll
    for (int i = 0; i < 4; ++i) {
        int idx = i * 256 + tid;
        e[i] = (idx < L) ? expf(v[i] - mx) : 0.f;
        sm += e[i];
    }
    sm = block_sum(sm);
    float inv = 1.f / sm;
    #pragma unroll
    for (int i = 0; i < 4; ++i)
        Prow[i * 256 + tid] = f2bf(e[i] * inv);
}

// ---------------- PV batched bf16 MFMA GEMM (causal K early-exit, dbuf) ---------
// P: [16][T,T] bf16; Vt: [4 kv][HD,T] bf16; out bf16 [B*T, NH*HD]
// grid (HD/128=2, T/128=8, 16)
__global__ __launch_bounds__(256) void pv_gemm(
    const unsigned short* __restrict__ P, const unsigned short* __restrict__ Vt,
    unsigned short* __restrict__ Out)
{
    int z = blockIdx.z;
    int b = z >> 3;
    int h = z & 7;
    const unsigned short* A  = P  + (size_t)z * T_ * T_;
    const unsigned short* Bm = Vt + (size_t)(z >> 2) * HD_ * T_;

    __shared__ unsigned short As[8192];
    __shared__ unsigned short Bs[8192];
    int tid = threadIdx.x;
    int lane = tid & 63;
    int wave = tid >> 6;
    int m0 = blockIdx.y * 128, n0 = blockIdx.x * 128;
    int Kend = m0 + 128;      // rows in this tile only attend keys < m0+128
    int wm = (wave >> 1) * 64;
    int wn = (wave & 1) * 64;
    floatx4 acc[4][4] = {};

    const unsigned short* aG0 = A  + (size_t)(m0 + lane)      * T_ + wave * 8;
    const unsigned short* aG1 = A  + (size_t)(m0 + 64 + lane) * T_ + wave * 8;
    const unsigned short* bG0 = Bm + (size_t)(n0 + lane)      * T_ + wave * 8;
    const unsigned short* bG1 = Bm + (size_t)(n0 + 64 + lane) * T_ + wave * 8;

    int kc = lane >> 4, mr = lane & 15;

    {
        gl_lds16(aG0, &As[wave * 1024]);
        gl_lds16(aG1, &As[wave * 1024 + 512]);
        gl_lds16(bG0, &Bs[wave * 1024]);
        gl_lds16(bG1, &Bs[wave * 1024 + 512]);
    }
    __syncthreads();
    int cur = 0;
    for (int k0 = 0; k0 < Kend; k0 += 32) {
        if (k0 + 32 < Kend) {
            int nb = (cur ^ 1) * 4096;
            gl_lds16(aG0 + k0 + 32, &As[nb + wave * 1024]);
            gl_lds16(aG1 + k0 + 32, &As[nb + wave * 1024 + 512]);
            gl_lds16(bG0 + k0 + 32, &Bs[nb + wave * 1024]);
            gl_lds16(bG1 + k0 + 32, &Bs[nb + wave * 1024 + 512]);
        }
        int cb = cur * 4096;
        bf16x8 af[4], bfv[4];
        #pragma unroll
        for (int mi = 0; mi < 4; ++mi)
            af[mi] = *reinterpret_cast<const bf16x8*>(&As[cb + kc * 1024 + (wm + mi * 16 + mr) * 8]);
        #pragma unroll
        for (int ni = 0; ni < 4; ++ni)
            bfv[ni] = *reinterpret_cast<const bf16x8*>(&Bs[cb + kc * 1024 + (wn + ni * 16 + mr) * 8]);
        #pragma unroll
        for (int mi = 0; mi < 4; ++mi)
            #pragma unroll
            for (int ni = 0; ni < 4; ++ni)
                acc[mi][ni] = __builtin_amdgcn_mfma_f32_16x16x32_bf16(af[mi], bfv[ni], acc[mi][ni], 0, 0, 0);
        __syncthreads();
        cur ^= 1;
    }
    int quad = lane >> 4;
    #pragma unroll
    for (int mi = 0; mi < 4; ++mi)
        #pragma unroll
        for (int ni = 0; ni < 4; ++ni)
            #pragma unroll
            for (int r = 0; r < 4; ++r) {
                int row = m0 + wm + mi * 16 + quad * 4 + r;
                int col = n0 + wn + ni * 16 + mr;
                Out[((size_t)(b * T_ + row)) * (NH_ * HD_) + h * HD_ + col] =
                    f2bf(acc[mi][ni][r]);
            }
}

// ---------------- altup correct + output-scale on stream 0 ----------------------
__global__ __launch_bounds__(256) void correct_kernel(
    const float* __restrict__ act, const float* __restrict__ pred,
    const float* __restrict__ mc, const float* __restrict__ ccw,
    const float* __restrict__ cscale, float* __restrict__ out)
{
    size_t row = blockIdx.x;
    int tid = threadIdx.x;
    __shared__ float ms[4];
    __shared__ float cc[4];
    if (tid < 4) ms[tid] = mc[row * S_ + tid];
    __syncthreads();
    if (tid < 4) {
        float s = 1.f;
        #pragma unroll
        for (int i = 0; i < 4; ++i) s += ms[i] * ccw[tid * 4 + i];
        cc[tid] = s;
    }
    __syncthreads();
    const size_t STRIDE = (size_t)ROWS_ * H_;
    #pragma unroll
    for (int i = 0; i < 8; ++i) {
        size_t idx = row * H_ + i*256 + tid;
        float a  = act[idx];
        float p0 = pred[idx];
        float inn = a - p0;
        #pragma unroll
        for (int j = 0; j < 4; ++j) {
            float val = inn * cc[j] + pred[idx + (size_t)j * STRIDE];
            if (j == 0) val *= cscale[i*256 + tid];
            out[idx + (size_t)j * STRIDE] = val;
        }
    }
}

// ---------------- launcher ----------------
extern "C" void kernel_launch(void* const* d_in, const int* in_sizes, int n_in,
                              void* d_out, int out_size, void* d_ws, size_t ws_size,
                              hipStream_t stream)
{
    (void)in_sizes; (void)n_in; (void)out_size; (void)ws_size;
    const float* hidden         = (const float*)d_in[0];
    const float* cosp           = (const float*)d_in[1];
    const float* sinp           = (const float*)d_in[2];
    const float* wq             = (const float*)d_in[3];
    const float* wk             = (const float*)d_in[4];
    const float* wv             = (const float*)d_in[5];
    const float* wo             = (const float*)d_in[6];
    const float* q_norm_w       = (const float*)d_in[7];
    const float* k_norm_w       = (const float*)d_in[8];
    const float* input_ln_w     = (const float*)d_in[9];
    const float* post_attn_ln_w = (const float*)d_in[10];
    const float* pre_ffw_ln_w   = (const float*)d_in[11];
    const float* post_ffw_ln_w  = (const float*)d_in[12];
    const float* gate_w         = (const float*)d_in[13];
    const float* up_w           = (const float*)d_in[14];
    const float* down_w         = (const float*)d_in[15];
    const float* ll_w           = (const float*)d_in[16];
    const float* lr_w           = (const float*)d_in[17];
    const float* laurel_norm_w  = (const float*)d_in[18];
    const float* router_norm_w  = (const float*)d_in[19];
    const float* router_w       = (const float*)d_in[20];
    const float* pred_coef_w    = (const float*)d_in[21];
    const float* corr_coef_w    = (const float*)d_in[22];
    const float* cscale         = (const float*)d_in[23];
    float* outp = (float*)d_out;

    char* base = (char*)d_ws;
    float* pred   = (float*)base;              base += 67108864;   // [4,R,H] fp32
    float* xnorm  = (float*)base;              base += 16777216;   // also split-K partial
    unsigned short* xnorm_bf = (unsigned short*)base; base += 8388608;
    float* lout   = (float*)base;              base += 16777216;
    float* alaur  = (float*)base;              base += 16777216;
    float* tmpH   = (float*)base;              base += 16777216;
    float* mbuf   = (float*)base;              base += 32768;
    float* mcbuf  = (float*)base;              base += 32768;
    float* ltmp   = (float*)base;              base += 524288;
    char* arena = base;                        // 100,663,296 B
    // attention phase layout
    unsigned short* qkvw_bf = (unsigned short*)arena;                 // 12,582,912 B
    float* qkv_pre = (float*)(arena + 12582912);                      // 25,165,824 B (dead after rope)
    unsigned short* Pbuf    = (unsigned short*)arena;                 // 33,554,432 B (16 heads bf16, over dead qkvw/qkv_pre)
    unsigned short* q_bf    = (unsigned short*)(arena + 37748736);    //  8,388,608 B
    unsigned short* k_bf    = (unsigned short*)(arena + 46137344);    //  2,097,152 B
    unsigned short* vT_bf   = (unsigned short*)(arena + 48234496);    //  2,097,152 B
    unsigned short* attn_bf = (unsigned short*)(arena + 50331648);    //  8,388,608 B
    unsigned short* wo_bf   = (unsigned short*)(arena + 58720256);    //  8,388,608 B
    float* Sbuf             = (float*)(arena + 67108864);             // 33,554,432 B (8 heads fp32)
    // MLP phase layout (aliases attention phase)
    unsigned short* gate_bf = (unsigned short*)arena;
    unsigned short* up_bf   = (unsigned short*)(arena + 33554432);
    unsigned short* gu_bf   = (unsigned short*)(arena + 67108864);
    unsigned short* down_bf = gate_bf;
    float* activated = lout;

    // ---- AltUp predict ----
    router_kernel <<<ROWS_, 256, 0, stream>>>(hidden, router_norm_w, router_w, mbuf);
    predict_kernel<<<ROWS_, 256, 0, stream>>>(hidden, mbuf, pred_coef_w, pred);
    ln_residual   <<<ROWS_, 256, 0, stream>>>(pred, nullptr, input_ln_w, nullptr, nullptr, 1.f, xnorm, xnorm_bf);

    // ---- Laurel (fp32, small) ----
    gemm_nt<<<dim3(LR_/BN, ROWS_/BM), 256, 0, stream>>>(xnorm, ll_w, ltmp, ROWS_, LR_, H_);
    gemm_nt<<<dim3(H_/BN,  ROWS_/BM), 256, 0, stream>>>(ltmp, lr_w, tmpH, ROWS_, H_, LR_);
    ln_residual<<<ROWS_, 256, 0, stream>>>(tmpH, nullptr, laurel_norm_w, xnorm, nullptr, 1.f, lout, nullptr);

    // ---- Attention ----
    cvt_bf16<<<2048, 256, 0, stream>>>(wq, qkvw_bf,            4194304);
    cvt_bf16<<< 512, 256, 0, stream>>>(wk, qkvw_bf + 4194304,  1048576);
    cvt_bf16<<< 512, 256, 0, stream>>>(wv, qkvw_bf + 5242880,  1048576);
    gemm_bf16nt<<<dim3(24, 16, 1), 256, 0, stream>>>(xnorm_bf, qkvw_bf, qkv_pre, nullptr, ROWS_, 3072, H_);
    qkv_norm_rope_fused<<<ROWS_*12, 256, 0, stream>>>(qkv_pre, q_norm_w, k_norm_w, cosp, sinp, q_bf, k_bf, vT_bf);
    cvt_bf16<<<2048, 256, 0, stream>>>(wo, wo_bf, 4194304);
    for (int hb = 0; hb < B_ * NH_; hb += 8) {
        qk_gemm       <<<dim3(8, 8, 8), 256, 0, stream>>>(q_bf, k_bf, Sbuf, hb);
        softmax_causal<<<dim3(T_, 8),   256, 0, stream>>>(Sbuf, Pbuf + (size_t)hb * T_ * T_);
    }
    pv_gemm<<<dim3(2, 8, 16), 256, 0, stream>>>(Pbuf, vT_bf, attn_bf);
    gemm_bf16nt<<<dim3(16, 16, 2), 256, 0, stream>>>(attn_bf, wo_bf, tmpH, xnorm, ROWS_, H_, NH_*HD_);
    ln_residual<<<ROWS_, 256, 0, stream>>>(tmpH, xnorm, post_attn_ln_w, pred, lout, 0.7071067811865475f, alaur, nullptr);

    // ---- MLP ----
    ln_residual<<<ROWS_, 256, 0, stream>>>(alaur, nullptr, pre_ffw_ln_w, nullptr, nullptr, 1.f, nullptr, xnorm_bf);
    cvt_bf16<<<8192, 256, 0, stream>>>(gate_w, gate_bf, 16777216);
    cvt_bf16<<<8192, 256, 0, stream>>>(up_w,   up_bf,   16777216);
    gemm_gateup_bf16<<<dim3(128, 16), 256, 0, stream>>>(xnorm_bf, gate_bf, up_bf, gu_bf, ROWS_, FF_, H_);
    cvt_bf16<<<8192, 256, 0, stream>>>(down_w, down_bf, 16777216);
    gemm_bf16nt<<<dim3(16, 16, 2), 256, 0, stream>>>(gu_bf, down_bf, tmpH, xnorm, ROWS_, H_, FF_);
    ln_residual<<<ROWS_, 256, 0, stream>>>(tmpH, xnorm, post_ffw_ln_w, alaur, nullptr, 1.f, activated, nullptr);

    // ---- AltUp correct ----
    router_kernel <<<ROWS_, 256, 0, stream>>>(activated, router_norm_w, router_w, mcbuf);
    correct_kernel<<<ROWS_, 256, 0, stream>>>(activated, pred, mcbuf, corr_coef_w, cscale, outp);
}

// Round 4
// 1115.640 us; speedup vs baseline: 1.0776x; 1.0603x over previous
//
#include <hip/hip_runtime.h>
#include <hip/hip_bf16.h>
#include <math.h>

#define B_   2
#define T_   1024
#define H_   2048
#define NH_  8
#define NKV_ 2
#define HD_  256
#define S_   4
#define FF_  8192
#define LR_  64
#define ROWS_ (B_*T_)          // 2048 tokens
#define EPS_ 1e-6f

typedef __attribute__((ext_vector_type(8))) __bf16 bf16x8;
typedef __attribute__((ext_vector_type(4))) float floatx4;
typedef __attribute__((ext_vector_type(8))) unsigned short ushort8v;

__device__ __forceinline__ unsigned short f2bf(float f) {
    unsigned int u = __float_as_uint(f);
    return (unsigned short)((u + 0x7FFFu + ((u >> 16) & 1u)) >> 16);
}

// async global->LDS, 16B per lane. LDS dest is wave-uniform base + lane*16.
__device__ __forceinline__ void gl_lds16(const void* g, void* l) {
    __builtin_amdgcn_global_load_lds(
        (const __attribute__((address_space(1))) void*)g,
        (__attribute__((address_space(3))) void*)l, 16, 0, 0);
}

// ---------------- block-wide reductions (256 threads = 4 waves) ----------------
__device__ __forceinline__ float block_sum(float v) {
    __shared__ float s4[4];
    #pragma unroll
    for (int o = 32; o > 0; o >>= 1) v += __shfl_down(v, o, 64);
    int lane = threadIdx.x & 63;
    int w    = threadIdx.x >> 6;
    __syncthreads();
    if (lane == 0) s4[w] = v;
    __syncthreads();
    return s4[0] + s4[1] + s4[2] + s4[3];
}

__device__ __forceinline__ float block_max(float v) {
    __shared__ float s4m[4];
    #pragma unroll
    for (int o = 32; o > 0; o >>= 1) v = fmaxf(v, __shfl_down(v, o, 64));
    int lane = threadIdx.x & 63;
    int w    = threadIdx.x >> 6;
    __syncthreads();
    if (lane == 0) s4m[w] = v;
    __syncthreads();
    return fmaxf(fmaxf(s4m[0], s4m[1]), fmaxf(s4m[2], s4m[3]));
}

// ---------------- fp32 -> bf16 convert (8 elements/thread) ----------------------
__global__ __launch_bounds__(256) void cvt_bf16(
    const float* __restrict__ in, unsigned short* __restrict__ out, int n)
{
    int i = (blockIdx.x * 256 + threadIdx.x) * 8;
    if (i >= n) return;
    float4 v0 = *reinterpret_cast<const float4*>(in + i);
    float4 v1 = *reinterpret_cast<const float4*>(in + i + 4);
    ushort8v o;
    o[0] = f2bf(v0.x); o[1] = f2bf(v0.y); o[2] = f2bf(v0.z); o[3] = f2bf(v0.w);
    o[4] = f2bf(v1.x); o[5] = f2bf(v1.y); o[6] = f2bf(v1.z); o[7] = f2bf(v1.w);
    *reinterpret_cast<ushort8v*>(out + i) = o;
}

// ---------------- router: m = tanh( (LN(x)*w_norm / H) @ router_w^T ) ----------
__global__ __launch_bounds__(256) void router_kernel(
    const float* __restrict__ x, const float* __restrict__ nw,
    const float* __restrict__ rw, float* __restrict__ mout)
{
    size_t row = blockIdx.x;
    int tid = threadIdx.x;
    const float* xr = x + row * H_;
    float v[8]; float s = 0.f;
    #pragma unroll
    for (int i = 0; i < 8; ++i) { v[i] = xr[i*256 + tid]; s += v[i]; }
    float mu = block_sum(s) * (1.f / H_);
    float ss = 0.f;
    #pragma unroll
    for (int i = 0; i < 8; ++i) { float c = v[i] - mu; ss += c * c; }
    float rstd = rsqrtf(block_sum(ss) * (1.f / H_) + EPS_);
    float n[8];
    #pragma unroll
    for (int i = 0; i < 8; ++i) n[i] = (v[i] - mu) * rstd * nw[i*256 + tid];
    for (int so = 0; so < S_; ++so) {
        float p = 0.f;
        #pragma unroll
        for (int i = 0; i < 8; ++i) p += n[i] * rw[(size_t)so * H_ + i*256 + tid];
        float dot = block_sum(p);
        if (tid == 0) mout[row * S_ + so] = tanhf(dot * (1.f / H_));
    }
}

// ---------------- altup predict ----------------
__global__ __launch_bounds__(256) void predict_kernel(
    const float* __restrict__ hid, const float* __restrict__ m,
    const float* __restrict__ pcw, float* __restrict__ pred)
{
    size_t row = blockIdx.x;
    int tid = threadIdx.x;
    __shared__ float ms[4];
    __shared__ float c[16];
    if (tid < 4) ms[tid] = m[row * S_ + tid];
    __syncthreads();
    if (tid < 16) {
        float s = 0.f;
        #pragma unroll
        for (int i = 0; i < 4; ++i) s += ms[i] * pcw[tid * 4 + i];
        c[tid] = s;
    }
    __syncthreads();
    const size_t STRIDE = (size_t)ROWS_ * H_;
    #pragma unroll
    for (int i = 0; i < 8; ++i) {
        size_t idx = row * H_ + i*256 + tid;
        float h0 = hid[idx];
        float h1 = hid[idx + STRIDE];
        float h2 = hid[idx + 2*STRIDE];
        float h3 = hid[idx + 3*STRIDE];
        float hv[4] = {h0, h1, h2, h3};
        #pragma unroll
        for (int j = 0; j < 4; ++j) {
            float val = hv[j] + h0*c[j*4+0] + h1*c[j*4+1] + h2*c[j*4+2] + h3*c[j*4+3];
            pred[idx + (size_t)j * STRIDE] = val;
        }
    }
}

// ---- LN (+ optional pre-add xadd, residuals a1/a2, scale, fp32/bf16 out) -------
__global__ __launch_bounds__(256) void ln_residual(
    const float* __restrict__ x, const float* __restrict__ xadd,
    const float* __restrict__ w,
    const float* __restrict__ a1, const float* __restrict__ a2,
    float scale, float* __restrict__ out, unsigned short* __restrict__ outb)
{
    size_t row = blockIdx.x;
    int tid = threadIdx.x;
    const float* xr = x + row * H_;
    const float* xa = xadd ? xadd + row * H_ : nullptr;
    float v[8]; float s = 0.f;
    #pragma unroll
    for (int i = 0; i < 8; ++i) {
        v[i] = xr[i*256 + tid];
        if (xa) v[i] += xa[i*256 + tid];
        s += v[i];
    }
    float mu = block_sum(s) * (1.f / H_);
    float ss = 0.f;
    #pragma unroll
    for (int i = 0; i < 8; ++i) { float c = v[i] - mu; ss += c * c; }
    float rstd = rsqrtf(block_sum(ss) * (1.f / H_) + EPS_);
    #pragma unroll
    for (int i = 0; i < 8; ++i) {
        size_t idx = row * H_ + i*256 + tid;
        float y = (v[i] - mu) * rstd * w[i*256 + tid];
        if (a1) y += a1[idx];
        if (a2) y += a2[idx];
        y *= scale;
        if (out)  out[idx]  = y;
        if (outb) outb[idx] = f2bf(y);
    }
}

// ---------------- fp32 GEMM (laurel only): C = A[M,K] * B[N,K]^T ----------------
#define BM 64
#define BN 64
#define BK 32
#define LDP 68

__global__ __launch_bounds__(256) void gemm_nt(
    const float* __restrict__ A, const float* __restrict__ Bm,
    float* __restrict__ C, int M, int N, int K)
{
    __shared__ float As[BK][LDP];
    __shared__ float Bs[BK][LDP];
    int tid = threadIdx.x;
    int n0 = blockIdx.x * BN;
    int m0 = blockIdx.y * BM;
    int tx = tid & 15, ty = tid >> 4;
    int lrow = tid >> 3;
    int lk   = (tid & 7) << 2;
    float acc[4][4] = {};
    for (int k0 = 0; k0 < K; k0 += BK) {
        #pragma unroll
        for (int r = 0; r < 2; ++r) {
            int row = lrow + r * 32;
            float4 a4 = *reinterpret_cast<const float4*>(&A[(size_t)(m0 + row) * K + k0 + lk]);
            As[lk+0][row] = a4.x; As[lk+1][row] = a4.y; As[lk+2][row] = a4.z; As[lk+3][row] = a4.w;
            float4 b4 = *reinterpret_cast<const float4*>(&Bm[(size_t)(n0 + row) * K + k0 + lk]);
            Bs[lk+0][row] = b4.x; Bs[lk+1][row] = b4.y; Bs[lk+2][row] = b4.z; Bs[lk+3][row] = b4.w;
        }
        __syncthreads();
        #pragma unroll
        for (int k = 0; k < BK; ++k) {
            float4 av = *reinterpret_cast<const float4*>(&As[k][ty << 2]);
            float4 bv = *reinterpret_cast<const float4*>(&Bs[k][tx << 2]);
            float a[4] = {av.x, av.y, av.z, av.w};
            float b[4] = {bv.x, bv.y, bv.z, bv.w};
            #pragma unroll
            for (int i = 0; i < 4; ++i)
                #pragma unroll
                for (int j = 0; j < 4; ++j)
                    acc[i][j] = fmaf(a[i], b[j], acc[i][j]);
        }
        __syncthreads();
    }
    #pragma unroll
    for (int i = 0; i < 4; ++i) {
        float4 o; o.x = acc[i][0]; o.y = acc[i][1]; o.z = acc[i][2]; o.w = acc[i][3];
        *reinterpret_cast<float4*>(&C[(size_t)(m0 + (ty << 2) + i) * N + n0 + (tx << 2)]) = o;
    }
}

// ---------------- bf16 MFMA GEMM, coalesced gl_lds + LDS double-buffer ----------
// C[M,N] (fp32) = A_bf16[M,K] * B_bf16[N,K]^T.  128x128 tile, BK=32.
// LDS layout: [buf:2][row:128][32 shorts] (row-major K-slab).
// Staging: wave w owns rows w*16..+15 (and +64); lane l -> row l>>2, k-chunk l&3.
//   -> LDS dest linear in lane (HW requirement), global src 64B/4-lane coalesced.
// grid.z = split-K: z==0 -> C, z==1 -> C2 (consumer sums).
__global__ __launch_bounds__(256) void gemm_bf16nt(
    const unsigned short* __restrict__ A, const unsigned short* __restrict__ Bm,
    float* __restrict__ C, float* __restrict__ C2, int M, int N, int K)
{
    __shared__ unsigned short As[8192];   // [2][128][32]
    __shared__ unsigned short Bs[8192];
    int tid = threadIdx.x;
    int lane = tid & 63;
    int wave = tid >> 6;
    int m0 = blockIdx.y * 128, n0 = blockIdx.x * 128;
    int Kper = K / gridDim.z;
    int kbeg = blockIdx.z * Kper;
    int kend = kbeg + Kper;
    int wm = (wave >> 1) * 64;
    int wn = (wave & 1) * 64;
    floatx4 acc[4][4] = {};

    int lr = lane >> 2;      // row within 16-row group
    int lc = lane & 3;       // k-chunk slot (8 shorts)
    const unsigned short* aG0 = A  + (size_t)(m0 + wave*16 + lr) * K + lc * 8;
    const unsigned short* aG1 = aG0 + (size_t)64 * K;
    const unsigned short* bG0 = Bm + (size_t)(n0 + wave*16 + lr) * K + lc * 8;
    const unsigned short* bG1 = bG0 + (size_t)64 * K;

    int kc = lane >> 4, mr = lane & 15;

    // prologue: stage first tile into buf 0
    gl_lds16(aG0 + kbeg, &As[wave * 512]);
    gl_lds16(aG1 + kbeg, &As[2048 + wave * 512]);
    gl_lds16(bG0 + kbeg, &Bs[wave * 512]);
    gl_lds16(bG1 + kbeg, &Bs[2048 + wave * 512]);
    __syncthreads();
    int cur = 0;
    for (int k0 = kbeg; k0 < kend; k0 += 32) {
        if (k0 + 32 < kend) {           // prefetch next tile into other buffer
            int nb = (cur ^ 1) * 4096;
            gl_lds16(aG0 + k0 + 32, &As[nb + wave * 512]);
            gl_lds16(aG1 + k0 + 32, &As[nb + 2048 + wave * 512]);
            gl_lds16(bG0 + k0 + 32, &Bs[nb + wave * 512]);
            gl_lds16(bG1 + k0 + 32, &Bs[nb + 2048 + wave * 512]);
        }
        int cb = cur * 4096;
        bf16x8 af[4], bfv[4];
        #pragma unroll
        for (int mi = 0; mi < 4; ++mi)
            af[mi] = *reinterpret_cast<const bf16x8*>(&As[cb + (wm + mi * 16 + mr) * 32 + kc * 8]);
        #pragma unroll
        for (int ni = 0; ni < 4; ++ni)
            bfv[ni] = *reinterpret_cast<const bf16x8*>(&Bs[cb + (wn + ni * 16 + mr) * 32 + kc * 8]);
        #pragma unroll
        for (int mi = 0; mi < 4; ++mi)
            #pragma unroll
            for (int ni = 0; ni < 4; ++ni)
                acc[mi][ni] = __builtin_amdgcn_mfma_f32_16x16x32_bf16(af[mi], bfv[ni], acc[mi][ni], 0, 0, 0);
        __syncthreads();   // drains prefetch vmcnt + fences reads of cur
        cur ^= 1;
    }
    float* Cout = (blockIdx.z == 0) ? C : C2;
    int quad = lane >> 4;
    #pragma unroll
    for (int mi = 0; mi < 4; ++mi)
        #pragma unroll
        for (int ni = 0; ni < 4; ++ni)
            #pragma unroll
            for (int r = 0; r < 4; ++r)
                Cout[(size_t)(m0 + wm + mi * 16 + quad * 4 + r) * N + n0 + wn + ni * 16 + mr] = acc[mi][ni][r];
}

// ---------------- fused gate/up bf16 GEMM -> gu_bf16 = gelu(A*G^T)*(A*U^T) ------
// BM=128, BN=128 ff-cols; wave tile 64x64 computing BOTH gate and up.
// LDS [2][128][32] per operand (A,G,U) = 48 KB. Coalesced gl_lds staging.
__global__ __launch_bounds__(256) void gemm_gateup_bf16(
    const unsigned short* __restrict__ A, const unsigned short* __restrict__ G,
    const unsigned short* __restrict__ U, unsigned short* __restrict__ Cbf,
    int M, int N, int K)
{
    __shared__ unsigned short As[8192];  // [2][128][32]
    __shared__ unsigned short Gs[8192];
    __shared__ unsigned short Us[8192];
    int tid = threadIdx.x;
    int lane = tid & 63;
    int wave = tid >> 6;
    int m0 = blockIdx.y * 128, n0 = blockIdx.x * 128;
    int wm  = (wave >> 1) * 64;
    int wnf = (wave & 1) * 64;
    floatx4 accg[4][4] = {};
    floatx4 accu[4][4] = {};

    int lr = lane >> 2;
    int lc = lane & 3;
    const unsigned short* aG0 = A + (size_t)(m0 + wave*16 + lr) * K + lc * 8;
    const unsigned short* aG1 = aG0 + (size_t)64 * K;
    const unsigned short* gG0 = G + (size_t)(n0 + wave*16 + lr) * K + lc * 8;
    const unsigned short* gG1 = gG0 + (size_t)64 * K;
    const unsigned short* uG0 = U + (size_t)(n0 + wave*16 + lr) * K + lc * 8;
    const unsigned short* uG1 = uG0 + (size_t)64 * K;

    int kc = lane >> 4, mr = lane & 15;

    gl_lds16(aG0, &As[wave * 512]);
    gl_lds16(aG1, &As[2048 + wave * 512]);
    gl_lds16(gG0, &Gs[wave * 512]);
    gl_lds16(gG1, &Gs[2048 + wave * 512]);
    gl_lds16(uG0, &Us[wave * 512]);
    gl_lds16(uG1, &Us[2048 + wave * 512]);
    __syncthreads();
    int cur = 0;
    for (int k0 = 0; k0 < K; k0 += 32) {
        if (k0 + 32 < K) {
            int nb = (cur ^ 1) * 4096;
            gl_lds16(aG0 + k0 + 32, &As[nb + wave * 512]);
            gl_lds16(aG1 + k0 + 32, &As[nb + 2048 + wave * 512]);
            gl_lds16(gG0 + k0 + 32, &Gs[nb + wave * 512]);
            gl_lds16(gG1 + k0 + 32, &Gs[nb + 2048 + wave * 512]);
            gl_lds16(uG0 + k0 + 32, &Us[nb + wave * 512]);
            gl_lds16(uG1 + k0 + 32, &Us[nb + 2048 + wave * 512]);
        }
        int cb = cur * 4096;
        bf16x8 af[4], gf[4], uf[4];
        #pragma unroll
        for (int mi = 0; mi < 4; ++mi)
            af[mi] = *reinterpret_cast<const bf16x8*>(&As[cb + (wm + mi * 16 + mr) * 32 + kc * 8]);
        #pragma unroll
        for (int ni = 0; ni < 4; ++ni) {
            gf[ni] = *reinterpret_cast<const bf16x8*>(&Gs[cb + (wnf + ni * 16 + mr) * 32 + kc * 8]);
            uf[ni] = *reinterpret_cast<const bf16x8*>(&Us[cb + (wnf + ni * 16 + mr) * 32 + kc * 8]);
        }
        #pragma unroll
        for (int mi = 0; mi < 4; ++mi)
            #pragma unroll
            for (int ni = 0; ni < 4; ++ni) {
                accg[mi][ni] = __builtin_amdgcn_mfma_f32_16x16x32_bf16(af[mi], gf[ni], accg[mi][ni], 0, 0, 0);
                accu[mi][ni] = __builtin_amdgcn_mfma_f32_16x16x32_bf16(af[mi], uf[ni], accu[mi][ni], 0, 0, 0);
            }
        __syncthreads();
        cur ^= 1;
    }
    int quad = lane >> 4;
    #pragma unroll
    for (int mi = 0; mi < 4; ++mi) {
        int rb = m0 + wm + mi * 16 + quad * 4;
        #pragma unroll
        for (int ni = 0; ni < 4; ++ni)
            #pragma unroll
            for (int r = 0; r < 4; ++r) {
                float g = accg[mi][ni][r];
                float gl = 0.5f * g * (1.f + tanhf(0.7978845608028654f * (g + 0.044715f * g * g * g)));
                float val = gl * accu[mi][ni][r];
                Cbf[(size_t)(rb + r) * N + n0 + wnf + ni * 16 + mr] = f2bf(val);
            }
    }
}

// ---------------- fused per-head LN + RoPE for q/k/v, bf16 out ------------------
// grid = ROWS_*12 ; hh: 0-7 = q heads, 8-9 = k heads, 10-11 = v heads (v transposed)
__global__ __launch_bounds__(256) void qkv_norm_rope_fused(
    const float* __restrict__ in, const float* __restrict__ qw,
    const float* __restrict__ kw,
    const float* __restrict__ cs, const float* __restrict__ sn,
    unsigned short* __restrict__ qo, unsigned short* __restrict__ ko,
    unsigned short* __restrict__ vo)
{
    int blk = blockIdx.x;
    int hh = blk % 12;
    int trow = blk / 12;
    int b = trow / T_;
    int t = trow % T_;
    int d = threadIdx.x;
    float x = in[(size_t)trow * 3072 + hh * HD_ + d];
    float mu = block_sum(x) * (1.f / HD_);
    float xc = x - mu;
    float var = block_sum(xc * xc) * (1.f / HD_);
    float wv_ = (hh < 8) ? qw[d] : (hh < 10 ? kw[d] : 1.f);
    float n = xc * rsqrtf(var + EPS_) * wv_;
    __shared__ float buf[HD_];
    buf[d] = n;
    __syncthreads();
    float val = n;
    if (hh < 10) {   // rope for q and k (block-uniform branch)
        float c = cs[(size_t)trow * HD_ + d];
        float s = sn[(size_t)trow * HD_ + d];
        float other = (d < 128) ? -buf[d + 128] : buf[d - 128];
        val = n * c + other * s;
    }
    if (hh < 8)
        qo[(((size_t)b * NH_ + hh) * T_ + t) * HD_ + d] = f2bf(val);
    else if (hh < 10)
        ko[(((size_t)b * NKV_ + (hh - 8)) * T_ + t) * HD_ + d] = f2bf(val);
    else
        vo[(((size_t)b * NKV_ + (hh - 10)) * HD_ + d) * T_ + t] = f2bf(val);
}

// ---------------- QK^T batched bf16 MFMA GEMM (causal tile-skip) ----------------
// Q: [16 heads][T,HD]; K: [4 kv][T,HD]; S: [8 heads of group][T,T] fp32
// grid (T/128, T/128, 8)
__global__ __launch_bounds__(256) void qk_gemm(
    const unsigned short* __restrict__ Q, const unsigned short* __restrict__ Kt,
    float* __restrict__ S, int head_base)
{
    if (blockIdx.x > blockIdx.y) return;   // tile fully above causal diagonal
    int z = blockIdx.z;
    int bh = head_base + z;
    const unsigned short* A  = Q  + (size_t)bh * T_ * HD_;
    const unsigned short* Bm = Kt + (size_t)(bh >> 2) * T_ * HD_;
    float* C = S + (size_t)z * T_ * T_;

    __shared__ unsigned short As[8192];
    __shared__ unsigned short Bs[8192];
    int tid = threadIdx.x;
    int lane = tid & 63;
    int wave = tid >> 6;
    int m0 = blockIdx.y * 128, n0 = blockIdx.x * 128;
    int wm = (wave >> 1) * 64;
    int wn = (wave & 1) * 64;
    floatx4 acc[4][4] = {};

    int lr = lane >> 2;
    int lc = lane & 3;
    const unsigned short* aG0 = A  + (size_t)(m0 + wave*16 + lr) * HD_ + lc * 8;
    const unsigned short* aG1 = aG0 + (size_t)64 * HD_;
    const unsigned short* bG0 = Bm + (size_t)(n0 + wave*16 + lr) * HD_ + lc * 8;
    const unsigned short* bG1 = bG0 + (size_t)64 * HD_;

    int kc = lane >> 4, mr = lane & 15;

    gl_lds16(aG0, &As[wave * 512]);
    gl_lds16(aG1, &As[2048 + wave * 512]);
    gl_lds16(bG0, &Bs[wave * 512]);
    gl_lds16(bG1, &Bs[2048 + wave * 512]);
    __syncthreads();
    int cur = 0;
    for (int k0 = 0; k0 < HD_; k0 += 32) {
        if (k0 + 32 < HD_) {
            int nb = (cur ^ 1) * 4096;
            gl_lds16(aG0 + k0 + 32, &As[nb + wave * 512]);
            gl_lds16(aG1 + k0 + 32, &As[nb + 2048 + wave * 512]);
            gl_lds16(bG0 + k0 + 32, &Bs[nb + wave * 512]);
            gl_lds16(bG1 + k0 + 32, &Bs[nb + 2048 + wave * 512]);
        }
        int cb = cur * 4096;
        bf16x8 af[4], bfv[4];
        #pragma unroll
        for (int mi = 0; mi < 4; ++mi)
            af[mi] = *reinterpret_cast<const bf16x8*>(&As[cb + (wm + mi * 16 + mr) * 32 + kc * 8]);
        #pragma unroll
        for (int ni = 0; ni < 4; ++ni)
            bfv[ni] = *reinterpret_cast<const bf16x8*>(&Bs[cb + (wn + ni * 16 + mr) * 32 + kc * 8]);
        #pragma unroll
        for (int mi = 0; mi < 4; ++mi)
            #pragma unroll
            for (int ni = 0; ni < 4; ++ni)
                acc[mi][ni] = __builtin_amdgcn_mfma_f32_16x16x32_bf16(af[mi], bfv[ni], acc[mi][ni], 0, 0, 0);
        __syncthreads();
        cur ^= 1;
    }
    int quad = lane >> 4;
    #pragma unroll
    for (int mi = 0; mi < 4; ++mi)
        #pragma unroll
        for (int ni = 0; ni < 4; ++ni)
            #pragma unroll
            for (int r = 0; r < 4; ++r)
                C[(size_t)(m0 + wm + mi * 16 + quad * 4 + r) * T_ + n0 + wn + ni * 16 + mr] = acc[mi][ni][r];
}

// ---------------- causal softmax: fp32 scores row -> bf16 probs row -------------
// grid (T, 8): x=query row, y=head-in-group. Writes zeros above diagonal.
__global__ __launch_bounds__(256) void softmax_causal(
    const float* __restrict__ S, unsigned short* __restrict__ P)
{
    int qi = blockIdx.x;
    int g  = blockIdx.y;
    int tid = threadIdx.x;
    int L = qi + 1;
    const float* Srow = S + ((size_t)g * T_ + qi) * T_;
    unsigned short* Prow = P + ((size_t)g * T_ + qi) * T_;
    float v[4];
    float mx = -3.402823466e38f;
    #pragma unroll
    for (int i = 0; i < 4; ++i) {
        int idx = i * 256 + tid;
        v[i] = (idx < L) ? Srow[idx] : -3.402823466e38f;
        mx = fmaxf(mx, v[i]);
    }
    mx = block_max(mx);
    float sm = 0.f;
    float e[4];
    #pragma unroll
    for (int i = 0; i < 4; ++i) {
        int idx = i * 256 + tid;
        e[i] = (idx < L) ? expf(v[i] - mx) : 0.f;
        sm += e[i];
    }
    sm = block_sum(sm);
    float inv = 1.f / sm;
    #pragma unroll
    for (int i = 0; i < 4; ++i)
        Prow[i * 256 + tid] = f2bf(e[i] * inv);
}

// ---------------- PV batched bf16 MFMA GEMM (causal K early-exit) ---------------
// P: [16][T,T] bf16; Vt: [4 kv][HD,T] bf16; out bf16 [B*T, NH*HD]
// grid (HD/128=2, T/128=8, 16)
__global__ __launch_bounds__(256) void pv_gemm(
    const unsigned short* __restrict__ P, const unsigned short* __restrict__ Vt,
    unsigned short* __restrict__ Out)
{
    int z = blockIdx.z;
    int b = z >> 3;
    int h = z & 7;
    const unsigned short* A  = P  + (size_t)z * T_ * T_;
    const unsigned short* Bm = Vt + (size_t)(z >> 2) * HD_ * T_;

    __shared__ unsigned short As[8192];
    __shared__ unsigned short Bs[8192];
    int tid = threadIdx.x;
    int lane = tid & 63;
    int wave = tid >> 6;
    int m0 = blockIdx.y * 128, n0 = blockIdx.x * 128;
    int Kend = m0 + 128;      // rows in this tile only attend keys < m0+128
    int wm = (wave >> 1) * 64;
    int wn = (wave & 1) * 64;
    floatx4 acc[4][4] = {};

    int lr = lane >> 2;
    int lc = lane & 3;
    const unsigned short* aG0 = A  + (size_t)(m0 + wave*16 + lr) * T_ + lc * 8;
    const unsigned short* aG1 = aG0 + (size_t)64 * T_;
    const unsigned short* bG0 = Bm + (size_t)(n0 + wave*16 + lr) * T_ + lc * 8;
    const unsigned short* bG1 = bG0 + (size_t)64 * T_;

    int kc = lane >> 4, mr = lane & 15;

    gl_lds16(aG0, &As[wave * 512]);
    gl_lds16(aG1, &As[2048 + wave * 512]);
    gl_lds16(bG0, &Bs[wave * 512]);
    gl_lds16(bG1, &Bs[2048 + wave * 512]);
    __syncthreads();
    int cur = 0;
    for (int k0 = 0; k0 < Kend; k0 += 32) {
        if (k0 + 32 < Kend) {
            int nb = (cur ^ 1) * 4096;
            gl_lds16(aG0 + k0 + 32, &As[nb + wave * 512]);
            gl_lds16(aG1 + k0 + 32, &As[nb + 2048 + wave * 512]);
            gl_lds16(bG0 + k0 + 32, &Bs[nb + wave * 512]);
            gl_lds16(bG1 + k0 + 32, &Bs[nb + 2048 + wave * 512]);
        }
        int cb = cur * 4096;
        bf16x8 af[4], bfv[4];
        #pragma unroll
        for (int mi = 0; mi < 4; ++mi)
            af[mi] = *reinterpret_cast<const bf16x8*>(&As[cb + (wm + mi * 16 + mr) * 32 + kc * 8]);
        #pragma unroll
        for (int ni = 0; ni < 4; ++ni)
            bfv[ni] = *reinterpret_cast<const bf16x8*>(&Bs[cb + (wn + ni * 16 + mr) * 32 + kc * 8]);
        #pragma unroll
        for (int mi = 0; mi < 4; ++mi)
            #pragma unroll
            for (int ni = 0; ni < 4; ++ni)
                acc[mi][ni] = __builtin_amdgcn_mfma_f32_16x16x32_bf16(af[mi], bfv[ni], acc[mi][ni], 0, 0, 0);
        __syncthreads();
        cur ^= 1;
    }
    int quad = lane >> 4;
    #pragma unroll
    for (int mi = 0; mi < 4; ++mi)
        #pragma unroll
        for (int ni = 0; ni < 4; ++ni)
            #pragma unroll
            for (int r = 0; r < 4; ++r) {
                int row = m0 + wm + mi * 16 + quad * 4 + r;
                int col = n0 + wn + ni * 16 + mr;
                Out[((size_t)(b * T_ + row)) * (NH_ * HD_) + h * HD_ + col] =
                    f2bf(acc[mi][ni][r]);
            }
}

// ---------------- altup correct + output-scale on stream 0 ----------------------
__global__ __launch_bounds__(256) void correct_kernel(
    const float* __restrict__ act, const float* __restrict__ pred,
    const float* __restrict__ mc, const float* __restrict__ ccw,
    const float* __restrict__ cscale, float* __restrict__ out)
{
    size_t row = blockIdx.x;
    int tid = threadIdx.x;
    __shared__ float ms[4];
    __shared__ float cc[4];
    if (tid < 4) ms[tid] = mc[row * S_ + tid];
    __syncthreads();
    if (tid < 4) {
        float s = 1.f;
        #pragma unroll
        for (int i = 0; i < 4; ++i) s += ms[i] * ccw[tid * 4 + i];
        cc[tid] = s;
    }
    __syncthreads();
    const size_t STRIDE = (size_t)ROWS_ * H_;
    #pragma unroll
    for (int i = 0; i < 8; ++i) {
        size_t idx = row * H_ + i*256 + tid;
        float a  = act[idx];
        float p0 = pred[idx];
        float inn = a - p0;
        #pragma unroll
        for (int j = 0; j < 4; ++j) {
            float val = inn * cc[j] + pred[idx + (size_t)j * STRIDE];
            if (j == 0) val *= cscale[i*256 + tid];
            out[idx + (size_t)j * STRIDE] = val;
        }
    }
}

// ---------------- launcher ----------------
extern "C" void kernel_launch(void* const* d_in, const int* in_sizes, int n_in,
                              void* d_out, int out_size, void* d_ws, size_t ws_size,
                              hipStream_t stream)
{
    (void)in_sizes; (void)n_in; (void)out_size; (void)ws_size;
    const float* hidden         = (const float*)d_in[0];
    const float* cosp           = (const float*)d_in[1];
    const float* sinp           = (const float*)d_in[2];
    const float* wq             = (const float*)d_in[3];
    const float* wk             = (const float*)d_in[4];
    const float* wv             = (const float*)d_in[5];
    const float* wo             = (const float*)d_in[6];
    const float* q_norm_w       = (const float*)d_in[7];
    const float* k_norm_w       = (const float*)d_in[8];
    const float* input_ln_w     = (const float*)d_in[9];
    const float* post_attn_ln_w = (const float*)d_in[10];
    const float* pre_ffw_ln_w   = (const float*)d_in[11];
    const float* post_ffw_ln_w  = (const float*)d_in[12];
    const float* gate_w         = (const float*)d_in[13];
    const float* up_w           = (const float*)d_in[14];
    const float* down_w         = (const float*)d_in[15];
    const float* ll_w           = (const float*)d_in[16];
    const float* lr_w           = (const float*)d_in[17];
    const float* laurel_norm_w  = (const float*)d_in[18];
    const float* router_norm_w  = (const float*)d_in[19];
    const float* router_w       = (const float*)d_in[20];
    const float* pred_coef_w    = (const float*)d_in[21];
    const float* corr_coef_w    = (const float*)d_in[22];
    const float* cscale         = (const float*)d_in[23];
    float* outp = (float*)d_out;

    char* base = (char*)d_ws;
    float* pred   = (float*)base;              base += 67108864;   // [4,R,H] fp32
    float* xnorm  = (float*)base;              base += 16777216;   // also split-K partial
    unsigned short* xnorm_bf = (unsigned short*)base; base += 8388608;
    float* lout   = (float*)base;              base += 16777216;
    float* alaur  = (float*)base;              base += 16777216;
    float* tmpH   = (float*)base;              base += 16777216;
    float* mbuf   = (float*)base;              base += 32768;
    float* mcbuf  = (float*)base;              base += 32768;
    float* ltmp   = (float*)base;              base += 524288;
    char* arena = base;                        // 100,663,296 B
    // attention phase layout
    unsigned short* qkvw_bf = (unsigned short*)arena;                 // 12,582,912 B
    float* qkv_pre = (float*)(arena + 12582912);                      // 25,165,824 B (dead after rope)
    unsigned short* Pbuf    = (unsigned short*)arena;                 // 33,554,432 B (16 heads bf16, over dead qkvw/qkv_pre)
    unsigned short* q_bf    = (unsigned short*)(arena + 37748736);    //  8,388,608 B
    unsigned short* k_bf    = (unsigned short*)(arena + 46137344);    //  2,097,152 B
    unsigned short* vT_bf   = (unsigned short*)(arena + 48234496);    //  2,097,152 B
    unsigned short* attn_bf = (unsigned short*)(arena + 50331648);    //  8,388,608 B
    unsigned short* wo_bf   = (unsigned short*)(arena + 58720256);    //  8,388,608 B
    float* Sbuf             = (float*)(arena + 67108864);             // 33,554,432 B (8 heads fp32)
    // MLP phase layout (aliases attention phase)
    unsigned short* gate_bf = (unsigned short*)arena;
    unsigned short* up_bf   = (unsigned short*)(arena + 33554432);
    unsigned short* gu_bf   = (unsigned short*)(arena + 67108864);
    unsigned short* down_bf = gate_bf;
    float* activated = lout;

    // ---- AltUp predict ----
    router_kernel <<<ROWS_, 256, 0, stream>>>(hidden, router_norm_w, router_w, mbuf);
    predict_kernel<<<ROWS_, 256, 0, stream>>>(hidden, mbuf, pred_coef_w, pred);
    ln_residual   <<<ROWS_, 256, 0, stream>>>(pred, nullptr, input_ln_w, nullptr, nullptr, 1.f, xnorm, xnorm_bf);

    // ---- Laurel (fp32, small) ----
    gemm_nt<<<dim3(LR_/BN, ROWS_/BM), 256, 0, stream>>>(xnorm, ll_w, ltmp, ROWS_, LR_, H_);
    gemm_nt<<<dim3(H_/BN,  ROWS_/BM), 256, 0, stream>>>(ltmp, lr_w, tmpH, ROWS_, H_, LR_);
    ln_residual<<<ROWS_, 256, 0, stream>>>(tmpH, nullptr, laurel_norm_w, xnorm, nullptr, 1.f, lout, nullptr);

    // ---- Attention ----
    cvt_bf16<<<2048, 256, 0, stream>>>(wq, qkvw_bf,            4194304);
    cvt_bf16<<< 512, 256, 0, stream>>>(wk, qkvw_bf + 4194304,  1048576);
    cvt_bf16<<< 512, 256, 0, stream>>>(wv, qkvw_bf + 5242880,  1048576);
    gemm_bf16nt<<<dim3(24, 16, 1), 256, 0, stream>>>(xnorm_bf, qkvw_bf, qkv_pre, nullptr, ROWS_, 3072, H_);
    qkv_norm_rope_fused<<<ROWS_*12, 256, 0, stream>>>(qkv_pre, q_norm_w, k_norm_w, cosp, sinp, q_bf, k_bf, vT_bf);
    cvt_bf16<<<2048, 256, 0, stream>>>(wo, wo_bf, 4194304);
    for (int hb = 0; hb < B_ * NH_; hb += 8) {
        qk_gemm       <<<dim3(8, 8, 8), 256, 0, stream>>>(q_bf, k_bf, Sbuf, hb);
        softmax_causal<<<dim3(T_, 8),   256, 0, stream>>>(Sbuf, Pbuf + (size_t)hb * T_ * T_);
    }
    pv_gemm<<<dim3(2, 8, 16), 256, 0, stream>>>(Pbuf, vT_bf, attn_bf);
    gemm_bf16nt<<<dim3(16, 16, 2), 256, 0, stream>>>(attn_bf, wo_bf, tmpH, xnorm, ROWS_, H_, NH_*HD_);
    ln_residual<<<ROWS_, 256, 0, stream>>>(tmpH, xnorm, post_attn_ln_w, pred, lout, 0.7071067811865475f, alaur, nullptr);

    // ---- MLP ----
    ln_residual<<<ROWS_, 256, 0, stream>>>(alaur, nullptr, pre_ffw_ln_w, nullptr, nullptr, 1.f, nullptr, xnorm_bf);
    cvt_bf16<<<8192, 256, 0, stream>>>(gate_w, gate_bf, 16777216);
    cvt_bf16<<<8192, 256, 0, stream>>>(up_w,   up_bf,   16777216);
    gemm_gateup_bf16<<<dim3(64, 16), 256, 0, stream>>>(xnorm_bf, gate_bf, up_bf, gu_bf, ROWS_, FF_, H_);
    cvt_bf16<<<8192, 256, 0, stream>>>(down_w, down_bf, 16777216);
    gemm_bf16nt<<<dim3(16, 16, 2), 256, 0, stream>>>(gu_bf, down_bf, tmpH, xnorm, ROWS_, H_, FF_);
    ln_residual<<<ROWS_, 256, 0, stream>>>(tmpH, xnorm, post_ffw_ln_w, alaur, nullptr, 1.f, activated, nullptr);

    // ---- AltUp correct ----
    router_kernel <<<ROWS_, 256, 0, stream>>>(activated, router_norm_w, router_w, mcbuf);
    correct_kernel<<<ROWS_, 256, 0, stream>>>(activated, pred, mcbuf, corr_coef_w, cscale, outp);
}

// Round 5
// 1114.470 us; speedup vs baseline: 1.0787x; 1.0011x over previous
//
#include <hip/hip_runtime.h>
#include <hip/hip_bf16.h>
#include <math.h>

#define B_   2
#define T_   1024
#define H_   2048
#define NH_  8
#define NKV_ 2
#define HD_  256
#define S_   4
#define FF_  8192
#define LR_  64
#define ROWS_ (B_*T_)          // 2048 tokens
#define EPS_ 1e-6f

typedef __attribute__((ext_vector_type(8))) __bf16 bf16x8;
typedef __attribute__((ext_vector_type(4))) float floatx4;
typedef __attribute__((ext_vector_type(8))) unsigned short ushort8v;

__device__ __forceinline__ unsigned short f2bf(float f) {
    unsigned int u = __float_as_uint(f);
    return (unsigned short)((u + 0x7FFFu + ((u >> 16) & 1u)) >> 16);
}

// async global->LDS, 16B per lane. LDS dest is wave-uniform base + lane*16.
__device__ __forceinline__ void gl_lds16(const void* g, void* l) {
    __builtin_amdgcn_global_load_lds(
        (const __attribute__((address_space(1))) void*)g,
        (__attribute__((address_space(3))) void*)l, 16, 0, 0);
}

// LDS bank swizzle: physical 16B slot for (row, kc) = kc ^ sigma(row&15).
// sigma spreads the 4 k-chunk slots across rows so a 16-lane ds_read_b128
// column-read hits each 4-bank slot exactly twice (2-way = free).
__device__ __forceinline__ int swz_sigma(int r15) {
    return (r15 & 3) ^ ((r15 >> 2) & 3);
}

// ---------------- block-wide reductions (256 threads = 4 waves) ----------------
__device__ __forceinline__ float block_sum(float v) {
    __shared__ float s4[4];
    #pragma unroll
    for (int o = 32; o > 0; o >>= 1) v += __shfl_down(v, o, 64);
    int lane = threadIdx.x & 63;
    int w    = threadIdx.x >> 6;
    __syncthreads();
    if (lane == 0) s4[w] = v;
    __syncthreads();
    return s4[0] + s4[1] + s4[2] + s4[3];
}

__device__ __forceinline__ float block_max(float v) {
    __shared__ float s4m[4];
    #pragma unroll
    for (int o = 32; o > 0; o >>= 1) v = fmaxf(v, __shfl_down(v, o, 64));
    int lane = threadIdx.x & 63;
    int w    = threadIdx.x >> 6;
    __syncthreads();
    if (lane == 0) s4m[w] = v;
    __syncthreads();
    return fmaxf(fmaxf(s4m[0], s4m[1]), fmaxf(s4m[2], s4m[3]));
}

// ---------------- fp32 -> bf16 convert (8 elements/thread) ----------------------
__global__ __launch_bounds__(256) void cvt_bf16(
    const float* __restrict__ in, unsigned short* __restrict__ out, int n)
{
    int i = (blockIdx.x * 256 + threadIdx.x) * 8;
    if (i >= n) return;
    float4 v0 = *reinterpret_cast<const float4*>(in + i);
    float4 v1 = *reinterpret_cast<const float4*>(in + i + 4);
    ushort8v o;
    o[0] = f2bf(v0.x); o[1] = f2bf(v0.y); o[2] = f2bf(v0.z); o[3] = f2bf(v0.w);
    o[4] = f2bf(v1.x); o[5] = f2bf(v1.y); o[6] = f2bf(v1.z); o[7] = f2bf(v1.w);
    *reinterpret_cast<ushort8v*>(out + i) = o;
}

// ---------------- router: m = tanh( (LN(x)*w_norm / H) @ router_w^T ) ----------
__global__ __launch_bounds__(256) void router_kernel(
    const float* __restrict__ x, const float* __restrict__ nw,
    const float* __restrict__ rw, float* __restrict__ mout)
{
    size_t row = blockIdx.x;
    int tid = threadIdx.x;
    const float* xr = x + row * H_;
    float v[8]; float s = 0.f;
    #pragma unroll
    for (int i = 0; i < 8; ++i) { v[i] = xr[i*256 + tid]; s += v[i]; }
    float mu = block_sum(s) * (1.f / H_);
    float ss = 0.f;
    #pragma unroll
    for (int i = 0; i < 8; ++i) { float c = v[i] - mu; ss += c * c; }
    float rstd = rsqrtf(block_sum(ss) * (1.f / H_) + EPS_);
    float n[8];
    #pragma unroll
    for (int i = 0; i < 8; ++i) n[i] = (v[i] - mu) * rstd * nw[i*256 + tid];
    for (int so = 0; so < S_; ++so) {
        float p = 0.f;
        #pragma unroll
        for (int i = 0; i < 8; ++i) p += n[i] * rw[(size_t)so * H_ + i*256 + tid];
        float dot = block_sum(p);
        if (tid == 0) mout[row * S_ + so] = tanhf(dot * (1.f / H_));
    }
}

// ---------------- altup predict ----------------
__global__ __launch_bounds__(256) void predict_kernel(
    const float* __restrict__ hid, const float* __restrict__ m,
    const float* __restrict__ pcw, float* __restrict__ pred)
{
    size_t row = blockIdx.x;
    int tid = threadIdx.x;
    __shared__ float ms[4];
    __shared__ float c[16];
    if (tid < 4) ms[tid] = m[row * S_ + tid];
    __syncthreads();
    if (tid < 16) {
        float s = 0.f;
        #pragma unroll
        for (int i = 0; i < 4; ++i) s += ms[i] * pcw[tid * 4 + i];
        c[tid] = s;
    }
    __syncthreads();
    const size_t STRIDE = (size_t)ROWS_ * H_;
    #pragma unroll
    for (int i = 0; i < 8; ++i) {
        size_t idx = row * H_ + i*256 + tid;
        float h0 = hid[idx];
        float h1 = hid[idx + STRIDE];
        float h2 = hid[idx + 2*STRIDE];
        float h3 = hid[idx + 3*STRIDE];
        float hv[4] = {h0, h1, h2, h3};
        #pragma unroll
        for (int j = 0; j < 4; ++j) {
            float val = hv[j] + h0*c[j*4+0] + h1*c[j*4+1] + h2*c[j*4+2] + h3*c[j*4+3];
            pred[idx + (size_t)j * STRIDE] = val;
        }
    }
}

// ---- LN (+ optional pre-add xadd, residuals a1/a2, scale, fp32/bf16 out) -------
__global__ __launch_bounds__(256) void ln_residual(
    const float* __restrict__ x, const float* __restrict__ xadd,
    const float* __restrict__ w,
    const float* __restrict__ a1, const float* __restrict__ a2,
    float scale, float* __restrict__ out, unsigned short* __restrict__ outb)
{
    size_t row = blockIdx.x;
    int tid = threadIdx.x;
    const float* xr = x + row * H_;
    const float* xa = xadd ? xadd + row * H_ : nullptr;
    float v[8]; float s = 0.f;
    #pragma unroll
    for (int i = 0; i < 8; ++i) {
        v[i] = xr[i*256 + tid];
        if (xa) v[i] += xa[i*256 + tid];
        s += v[i];
    }
    float mu = block_sum(s) * (1.f / H_);
    float ss = 0.f;
    #pragma unroll
    for (int i = 0; i < 8; ++i) { float c = v[i] - mu; ss += c * c; }
    float rstd = rsqrtf(block_sum(ss) * (1.f / H_) + EPS_);
    #pragma unroll
    for (int i = 0; i < 8; ++i) {
        size_t idx = row * H_ + i*256 + tid;
        float y = (v[i] - mu) * rstd * w[i*256 + tid];
        if (a1) y += a1[idx];
        if (a2) y += a2[idx];
        y *= scale;
        if (out)  out[idx]  = y;
        if (outb) outb[idx] = f2bf(y);
    }
}

// ---------------- fp32 GEMM (laurel only): C = A[M,K] * B[N,K]^T ----------------
#define BM 64
#define BN 64
#define BK 32
#define LDP 68

__global__ __launch_bounds__(256) void gemm_nt(
    const float* __restrict__ A, const float* __restrict__ Bm,
    float* __restrict__ C, int M, int N, int K)
{
    __shared__ float As[BK][LDP];
    __shared__ float Bs[BK][LDP];
    int tid = threadIdx.x;
    int n0 = blockIdx.x * BN;
    int m0 = blockIdx.y * BM;
    int tx = tid & 15, ty = tid >> 4;
    int lrow = tid >> 3;
    int lk   = (tid & 7) << 2;
    float acc[4][4] = {};
    for (int k0 = 0; k0 < K; k0 += BK) {
        #pragma unroll
        for (int r = 0; r < 2; ++r) {
            int row = lrow + r * 32;
            float4 a4 = *reinterpret_cast<const float4*>(&A[(size_t)(m0 + row) * K + k0 + lk]);
            As[lk+0][row] = a4.x; As[lk+1][row] = a4.y; As[lk+2][row] = a4.z; As[lk+3][row] = a4.w;
            float4 b4 = *reinterpret_cast<const float4*>(&Bm[(size_t)(n0 + row) * K + k0 + lk]);
            Bs[lk+0][row] = b4.x; Bs[lk+1][row] = b4.y; Bs[lk+2][row] = b4.z; Bs[lk+3][row] = b4.w;
        }
        __syncthreads();
        #pragma unroll
        for (int k = 0; k < BK; ++k) {
            float4 av = *reinterpret_cast<const float4*>(&As[k][ty << 2]);
            float4 bv = *reinterpret_cast<const float4*>(&Bs[k][tx << 2]);
            float a[4] = {av.x, av.y, av.z, av.w};
            float b[4] = {bv.x, bv.y, bv.z, bv.w};
            #pragma unroll
            for (int i = 0; i < 4; ++i)
                #pragma unroll
                for (int j = 0; j < 4; ++j)
                    acc[i][j] = fmaf(a[i], b[j], acc[i][j]);
        }
        __syncthreads();
    }
    #pragma unroll
    for (int i = 0; i < 4; ++i) {
        float4 o; o.x = acc[i][0]; o.y = acc[i][1]; o.z = acc[i][2]; o.w = acc[i][3];
        *reinterpret_cast<float4*>(&C[(size_t)(m0 + (ty << 2) + i) * N + n0 + (tx << 2)]) = o;
    }
}

// ---------------- bf16 MFMA GEMM, coalesced gl_lds + swizzle + dbuf -------------
// C[M,N] (fp32) = A_bf16[M,K] * B_bf16[N,K]^T.  128x128 tile, BK=32.
// LDS [buf:2][row:128][4 slots x 8 shorts]; slot(row,kc) = kc ^ sigma(row&15).
// Staging: lane l fetches global (row = w*16+(l>>2), kc = (l&3)^sigma(l>>2)),
// gl_lds writes linearly -> physical slot l&3 holds that kc. Coalescing kept
// (kc permutation stays inside the row's 64B segment).
// grid.z = split-K: z==0 -> C, z==1 -> C2 (consumer sums).
__global__ __launch_bounds__(256) void gemm_bf16nt(
    const unsigned short* __restrict__ A, const unsigned short* __restrict__ Bm,
    float* __restrict__ C, float* __restrict__ C2, int M, int N, int K)
{
    __shared__ unsigned short As[8192];   // [2][128][32]
    __shared__ unsigned short Bs[8192];
    int tid = threadIdx.x;
    int lane = tid & 63;
    int wave = tid >> 6;
    int m0 = blockIdx.y * 128, n0 = blockIdx.x * 128;
    int Kper = K / gridDim.z;
    int kbeg = blockIdx.z * Kper;
    int kend = kbeg + Kper;
    int wm = (wave >> 1) * 64;
    int wn = (wave & 1) * 64;
    floatx4 acc[4][4] = {};

    int lr = lane >> 2;                      // row within 16-row group
    int kcs = (lane & 3) ^ swz_sigma(lr);    // global k-chunk this lane fetches
    const unsigned short* aG0 = A  + (size_t)(m0 + wave*16 + lr) * K + kcs * 8;
    const unsigned short* aG1 = aG0 + (size_t)64 * K;
    const unsigned short* bG0 = Bm + (size_t)(n0 + wave*16 + lr) * K + kcs * 8;
    const unsigned short* bG1 = bG0 + (size_t)64 * K;

    int kc = lane >> 4, mr = lane & 15;
    int kcp = (kc ^ swz_sigma(mr)) * 8;      // physical slot offset for reads

    // prologue: stage first tile into buf 0
    gl_lds16(aG0 + kbeg, &As[wave * 512]);
    gl_lds16(aG1 + kbeg, &As[2048 + wave * 512]);
    gl_lds16(bG0 + kbeg, &Bs[wave * 512]);
    gl_lds16(bG1 + kbeg, &Bs[2048 + wave * 512]);
    __syncthreads();
    int cur = 0;
    for (int k0 = kbeg; k0 < kend; k0 += 32) {
        if (k0 + 32 < kend) {           // prefetch next tile into other buffer
            int nb = (cur ^ 1) * 4096;
            gl_lds16(aG0 + k0 + 32, &As[nb + wave * 512]);
            gl_lds16(aG1 + k0 + 32, &As[nb + 2048 + wave * 512]);
            gl_lds16(bG0 + k0 + 32, &Bs[nb + wave * 512]);
            gl_lds16(bG1 + k0 + 32, &Bs[nb + 2048 + wave * 512]);
        }
        int cb = cur * 4096;
        bf16x8 af[4], bfv[4];
        #pragma unroll
        for (int mi = 0; mi < 4; ++mi)
            af[mi] = *reinterpret_cast<const bf16x8*>(&As[cb + (wm + mi * 16 + mr) * 32 + kcp]);
        #pragma unroll
        for (int ni = 0; ni < 4; ++ni)
            bfv[ni] = *reinterpret_cast<const bf16x8*>(&Bs[cb + (wn + ni * 16 + mr) * 32 + kcp]);
        #pragma unroll
        for (int mi = 0; mi < 4; ++mi)
            #pragma unroll
            for (int ni = 0; ni < 4; ++ni)
                acc[mi][ni] = __builtin_amdgcn_mfma_f32_16x16x32_bf16(af[mi], bfv[ni], acc[mi][ni], 0, 0, 0);
        __syncthreads();   // drains prefetch vmcnt + fences reads of cur
        cur ^= 1;
    }
    float* Cout = (blockIdx.z == 0) ? C : C2;
    int quad = lane >> 4;
    #pragma unroll
    for (int mi = 0; mi < 4; ++mi)
        #pragma unroll
        for (int ni = 0; ni < 4; ++ni)
            #pragma unroll
            for (int r = 0; r < 4; ++r)
                Cout[(size_t)(m0 + wm + mi * 16 + quad * 4 + r) * N + n0 + wn + ni * 16 + mr] = acc[mi][ni][r];
}

// ---------------- fused gate/up bf16 GEMM -> gu_bf16 = gelu(A*G^T)*(A*U^T) ------
// BM=128, BN=128 ff-cols; wave tile 64x64 computing BOTH gate and up.
// Swizzled LDS as in gemm_bf16nt. LDS 48 KB.
__global__ __launch_bounds__(256) void gemm_gateup_bf16(
    const unsigned short* __restrict__ A, const unsigned short* __restrict__ G,
    const unsigned short* __restrict__ U, unsigned short* __restrict__ Cbf,
    int M, int N, int K)
{
    __shared__ unsigned short As[8192];  // [2][128][32]
    __shared__ unsigned short Gs[8192];
    __shared__ unsigned short Us[8192];
    int tid = threadIdx.x;
    int lane = tid & 63;
    int wave = tid >> 6;
    int m0 = blockIdx.y * 128, n0 = blockIdx.x * 128;
    int wm  = (wave >> 1) * 64;
    int wnf = (wave & 1) * 64;
    floatx4 accg[4][4] = {};
    floatx4 accu[4][4] = {};

    int lr = lane >> 2;
    int kcs = (lane & 3) ^ swz_sigma(lr);
    const unsigned short* aG0 = A + (size_t)(m0 + wave*16 + lr) * K + kcs * 8;
    const unsigned short* aG1 = aG0 + (size_t)64 * K;
    const unsigned short* gG0 = G + (size_t)(n0 + wave*16 + lr) * K + kcs * 8;
    const unsigned short* gG1 = gG0 + (size_t)64 * K;
    const unsigned short* uG0 = U + (size_t)(n0 + wave*16 + lr) * K + kcs * 8;
    const unsigned short* uG1 = uG0 + (size_t)64 * K;

    int kc = lane >> 4, mr = lane & 15;
    int kcp = (kc ^ swz_sigma(mr)) * 8;

    gl_lds16(aG0, &As[wave * 512]);
    gl_lds16(aG1, &As[2048 + wave * 512]);
    gl_lds16(gG0, &Gs[wave * 512]);
    gl_lds16(gG1, &Gs[2048 + wave * 512]);
    gl_lds16(uG0, &Us[wave * 512]);
    gl_lds16(uG1, &Us[2048 + wave * 512]);
    __syncthreads();
    int cur = 0;
    for (int k0 = 0; k0 < K; k0 += 32) {
        if (k0 + 32 < K) {
            int nb = (cur ^ 1) * 4096;
            gl_lds16(aG0 + k0 + 32, &As[nb + wave * 512]);
            gl_lds16(aG1 + k0 + 32, &As[nb + 2048 + wave * 512]);
            gl_lds16(gG0 + k0 + 32, &Gs[nb + wave * 512]);
            gl_lds16(gG1 + k0 + 32, &Gs[nb + 2048 + wave * 512]);
            gl_lds16(uG0 + k0 + 32, &Us[nb + wave * 512]);
            gl_lds16(uG1 + k0 + 32, &Us[nb + 2048 + wave * 512]);
        }
        int cb = cur * 4096;
        bf16x8 af[4], gf[4], uf[4];
        #pragma unroll
        for (int mi = 0; mi < 4; ++mi)
            af[mi] = *reinterpret_cast<const bf16x8*>(&As[cb + (wm + mi * 16 + mr) * 32 + kcp]);
        #pragma unroll
        for (int ni = 0; ni < 4; ++ni) {
            gf[ni] = *reinterpret_cast<const bf16x8*>(&Gs[cb + (wnf + ni * 16 + mr) * 32 + kcp]);
            uf[ni] = *reinterpret_cast<const bf16x8*>(&Us[cb + (wnf + ni * 16 + mr) * 32 + kcp]);
        }
        #pragma unroll
        for (int mi = 0; mi < 4; ++mi)
            #pragma unroll
            for (int ni = 0; ni < 4; ++ni) {
                accg[mi][ni] = __builtin_amdgcn_mfma_f32_16x16x32_bf16(af[mi], gf[ni], accg[mi][ni], 0, 0, 0);
                accu[mi][ni] = __builtin_amdgcn_mfma_f32_16x16x32_bf16(af[mi], uf[ni], accu[mi][ni], 0, 0, 0);
            }
        __syncthreads();
        cur ^= 1;
    }
    int quad = lane >> 4;
    #pragma unroll
    for (int mi = 0; mi < 4; ++mi) {
        int rb = m0 + wm + mi * 16 + quad * 4;
        #pragma unroll
        for (int ni = 0; ni < 4; ++ni)
            #pragma unroll
            for (int r = 0; r < 4; ++r) {
                float g = accg[mi][ni][r];
                float gl = 0.5f * g * (1.f + tanhf(0.7978845608028654f * (g + 0.044715f * g * g * g)));
                float val = gl * accu[mi][ni][r];
                Cbf[(size_t)(rb + r) * N + n0 + wnf + ni * 16 + mr] = f2bf(val);
            }
    }
}

// ---------------- fused per-head LN + RoPE for q/k/v, bf16 out ------------------
// grid = ROWS_*12 ; hh: 0-7 = q heads, 8-9 = k heads, 10-11 = v heads (v transposed)
__global__ __launch_bounds__(256) void qkv_norm_rope_fused(
    const float* __restrict__ in, const float* __restrict__ qw,
    const float* __restrict__ kw,
    const float* __restrict__ cs, const float* __restrict__ sn,
    unsigned short* __restrict__ qo, unsigned short* __restrict__ ko,
    unsigned short* __restrict__ vo)
{
    int blk = blockIdx.x;
    int hh = blk % 12;
    int trow = blk / 12;
    int b = trow / T_;
    int t = trow % T_;
    int d = threadIdx.x;
    float x = in[(size_t)trow * 3072 + hh * HD_ + d];
    float mu = block_sum(x) * (1.f / HD_);
    float xc = x - mu;
    float var = block_sum(xc * xc) * (1.f / HD_);
    float wv_ = (hh < 8) ? qw[d] : (hh < 10 ? kw[d] : 1.f);
    float n = xc * rsqrtf(var + EPS_) * wv_;
    __shared__ float buf[HD_];
    buf[d] = n;
    __syncthreads();
    float val = n;
    if (hh < 10) {   // rope for q and k (block-uniform branch)
        float c = cs[(size_t)trow * HD_ + d];
        float s = sn[(size_t)trow * HD_ + d];
        float other = (d < 128) ? -buf[d + 128] : buf[d - 128];
        val = n * c + other * s;
    }
    if (hh < 8)
        qo[(((size_t)b * NH_ + hh) * T_ + t) * HD_ + d] = f2bf(val);
    else if (hh < 10)
        ko[(((size_t)b * NKV_ + (hh - 8)) * T_ + t) * HD_ + d] = f2bf(val);
    else
        vo[(((size_t)b * NKV_ + (hh - 10)) * HD_ + d) * T_ + t] = f2bf(val);
}

// ---------------- QK^T batched bf16 MFMA GEMM (causal tile-skip) ----------------
// Q: [16 heads][T,HD]; K: [4 kv][T,HD]; S: [8 heads of group][T,T] fp32
// grid (T/128, T/128, 8). Swizzled LDS.
__global__ __launch_bounds__(256) void qk_gemm(
    const unsigned short* __restrict__ Q, const unsigned short* __restrict__ Kt,
    float* __restrict__ S, int head_base)
{
    if (blockIdx.x > blockIdx.y) return;   // tile fully above causal diagonal
    int z = blockIdx.z;
    int bh = head_base + z;
    const unsigned short* A  = Q  + (size_t)bh * T_ * HD_;
    const unsigned short* Bm = Kt + (size_t)(bh >> 2) * T_ * HD_;
    float* C = S + (size_t)z * T_ * T_;

    __shared__ unsigned short As[8192];
    __shared__ unsigned short Bs[8192];
    int tid = threadIdx.x;
    int lane = tid & 63;
    int wave = tid >> 6;
    int m0 = blockIdx.y * 128, n0 = blockIdx.x * 128;
    int wm = (wave >> 1) * 64;
    int wn = (wave & 1) * 64;
    floatx4 acc[4][4] = {};

    int lr = lane >> 2;
    int kcs = (lane & 3) ^ swz_sigma(lr);
    const unsigned short* aG0 = A  + (size_t)(m0 + wave*16 + lr) * HD_ + kcs * 8;
    const unsigned short* aG1 = aG0 + (size_t)64 * HD_;
    const unsigned short* bG0 = Bm + (size_t)(n0 + wave*16 + lr) * HD_ + kcs * 8;
    const unsigned short* bG1 = bG0 + (size_t)64 * HD_;

    int kc = lane >> 4, mr = lane & 15;
    int kcp = (kc ^ swz_sigma(mr)) * 8;

    gl_lds16(aG0, &As[wave * 512]);
    gl_lds16(aG1, &As[2048 + wave * 512]);
    gl_lds16(bG0, &Bs[wave * 512]);
    gl_lds16(bG1, &Bs[2048 + wave * 512]);
    __syncthreads();
    int cur = 0;
    for (int k0 = 0; k0 < HD_; k0 += 32) {
        if (k0 + 32 < HD_) {
            int nb = (cur ^ 1) * 4096;
            gl_lds16(aG0 + k0 + 32, &As[nb + wave * 512]);
            gl_lds16(aG1 + k0 + 32, &As[nb + 2048 + wave * 512]);
            gl_lds16(bG0 + k0 + 32, &Bs[nb + wave * 512]);
            gl_lds16(bG1 + k0 + 32, &Bs[nb + 2048 + wave * 512]);
        }
        int cb = cur * 4096;
        bf16x8 af[4], bfv[4];
        #pragma unroll
        for (int mi = 0; mi < 4; ++mi)
            af[mi] = *reinterpret_cast<const bf16x8*>(&As[cb + (wm + mi * 16 + mr) * 32 + kcp]);
        #pragma unroll
        for (int ni = 0; ni < 4; ++ni)
            bfv[ni] = *reinterpret_cast<const bf16x8*>(&Bs[cb + (wn + ni * 16 + mr) * 32 + kcp]);
        #pragma unroll
        for (int mi = 0; mi < 4; ++mi)
            #pragma unroll
            for (int ni = 0; ni < 4; ++ni)
                acc[mi][ni] = __builtin_amdgcn_mfma_f32_16x16x32_bf16(af[mi], bfv[ni], acc[mi][ni], 0, 0, 0);
        __syncthreads();
        cur ^= 1;
    }
    int quad = lane >> 4;
    #pragma unroll
    for (int mi = 0; mi < 4; ++mi)
        #pragma unroll
        for (int ni = 0; ni < 4; ++ni)
            #pragma unroll
            for (int r = 0; r < 4; ++r)
                C[(size_t)(m0 + wm + mi * 16 + quad * 4 + r) * T_ + n0 + wn + ni * 16 + mr] = acc[mi][ni][r];
}

// ---------------- causal softmax: fp32 scores row -> bf16 probs row -------------
// grid (T, 8): x=query row, y=head-in-group. Writes zeros above diagonal.
__global__ __launch_bounds__(256) void softmax_causal(
    const float* __restrict__ S, unsigned short* __restrict__ P)
{
    int qi = blockIdx.x;
    int g  = blockIdx.y;
    int tid = threadIdx.x;
    int L = qi + 1;
    const float* Srow = S + ((size_t)g * T_ + qi) * T_;
    unsigned short* Prow = P + ((size_t)g * T_ + qi) * T_;
    float v[4];
    float mx = -3.402823466e38f;
    #pragma unroll
    for (int i = 0; i < 4; ++i) {
        int idx = i * 256 + tid;
        v[i] = (idx < L) ? Srow[idx] : -3.402823466e38f;
        mx = fmaxf(mx, v[i]);
    }
    mx = block_max(mx);
    float sm = 0.f;
    float e[4];
    #pragma unroll
    for (int i = 0; i < 4; ++i) {
        int idx = i * 256 + tid;
        e[i] = (idx < L) ? expf(v[i] - mx) : 0.f;
        sm += e[i];
    }
    sm = block_sum(sm);
    float inv = 1.f / sm;
    #pragma unroll
    for (int i = 0; i < 4; ++i)
        Prow[i * 256 + tid] = f2bf(e[i] * inv);
}

// ---------------- PV batched bf16 MFMA GEMM (causal K early-exit) ---------------
// P: [16][T,T] bf16; Vt: [4 kv][HD,T] bf16; out bf16 [B*T, NH*HD]
// grid (HD/128=2, T/128=8, 16). Swizzled LDS.
__global__ __launch_bounds__(256) void pv_gemm(
    const unsigned short* __restrict__ P, const unsigned short* __restrict__ Vt,
    unsigned short* __restrict__ Out)
{
    int z = blockIdx.z;
    int b = z >> 3;
    int h = z & 7;
    const unsigned short* A  = P  + (size_t)z * T_ * T_;
    const unsigned short* Bm = Vt + (size_t)(z >> 2) * HD_ * T_;

    __shared__ unsigned short As[8192];
    __shared__ unsigned short Bs[8192];
    int tid = threadIdx.x;
    int lane = tid & 63;
    int wave = tid >> 6;
    int m0 = blockIdx.y * 128, n0 = blockIdx.x * 128;
    int Kend = m0 + 128;      // rows in this tile only attend keys < m0+128
    int wm = (wave >> 1) * 64;
    int wn = (wave & 1) * 64;
    floatx4 acc[4][4] = {};

    int lr = lane >> 2;
    int kcs = (lane & 3) ^ swz_sigma(lr);
    const unsigned short* aG0 = A  + (size_t)(m0 + wave*16 + lr) * T_ + kcs * 8;
    const unsigned short* aG1 = aG0 + (size_t)64 * T_;
    const unsigned short* bG0 = Bm + (size_t)(n0 + wave*16 + lr) * T_ + kcs * 8;
    const unsigned short* bG1 = bG0 + (size_t)64 * T_;

    int kc = lane >> 4, mr = lane & 15;
    int kcp = (kc ^ swz_sigma(mr)) * 8;

    gl_lds16(aG0, &As[wave * 512]);
    gl_lds16(aG1, &As[2048 + wave * 512]);
    gl_lds16(bG0, &Bs[wave * 512]);
    gl_lds16(bG1, &Bs[2048 + wave * 512]);
    __syncthreads();
    int cur = 0;
    for (int k0 = 0; k0 < Kend; k0 += 32) {
        if (k0 + 32 < Kend) {
            int nb = (cur ^ 1) * 4096;
            gl_lds16(aG0 + k0 + 32, &As[nb + wave * 512]);
            gl_lds16(aG1 + k0 + 32, &As[nb + 2048 + wave * 512]);
            gl_lds16(bG0 + k0 + 32, &Bs[nb + wave * 512]);
            gl_lds16(bG1 + k0 + 32, &Bs[nb + 2048 + wave * 512]);
        }
        int cb = cur * 4096;
        bf16x8 af[4], bfv[4];
        #pragma unroll
        for (int mi = 0; mi < 4; ++mi)
            af[mi] = *reinterpret_cast<const bf16x8*>(&As[cb + (wm + mi * 16 + mr) * 32 + kcp]);
        #pragma unroll
        for (int ni = 0; ni < 4; ++ni)
            bfv[ni] = *reinterpret_cast<const bf16x8*>(&Bs[cb + (wn + ni * 16 + mr) * 32 + kcp]);
        #pragma unroll
        for (int mi = 0; mi < 4; ++mi)
            #pragma unroll
            for (int ni = 0; ni < 4; ++ni)
                acc[mi][ni] = __builtin_amdgcn_mfma_f32_16x16x32_bf16(af[mi], bfv[ni], acc[mi][ni], 0, 0, 0);
        __syncthreads();
        cur ^= 1;
    }
    int quad = lane >> 4;
    #pragma unroll
    for (int mi = 0; mi < 4; ++mi)
        #pragma unroll
        for (int ni = 0; ni < 4; ++ni)
            #pragma unroll
            for (int r = 0; r < 4; ++r) {
                int row = m0 + wm + mi * 16 + quad * 4 + r;
                int col = n0 + wn + ni * 16 + mr;
                Out[((size_t)(b * T_ + row)) * (NH_ * HD_) + h * HD_ + col] =
                    f2bf(acc[mi][ni][r]);
            }
}

// ---------------- altup correct + output-scale on stream 0 ----------------------
__global__ __launch_bounds__(256) void correct_kernel(
    const float* __restrict__ act, const float* __restrict__ pred,
    const float* __restrict__ mc, const float* __restrict__ ccw,
    const float* __restrict__ cscale, float* __restrict__ out)
{
    size_t row = blockIdx.x;
    int tid = threadIdx.x;
    __shared__ float ms[4];
    __shared__ float cc[4];
    if (tid < 4) ms[tid] = mc[row * S_ + tid];
    __syncthreads();
    if (tid < 4) {
        float s = 1.f;
        #pragma unroll
        for (int i = 0; i < 4; ++i) s += ms[i] * ccw[tid * 4 + i];
        cc[tid] = s;
    }
    __syncthreads();
    const size_t STRIDE = (size_t)ROWS_ * H_;
    #pragma unroll
    for (int i = 0; i < 8; ++i) {
        size_t idx = row * H_ + i*256 + tid;
        float a  = act[idx];
        float p0 = pred[idx];
        float inn = a - p0;
        #pragma unroll
        for (int j = 0; j < 4; ++j) {
            float val = inn * cc[j] + pred[idx + (size_t)j * STRIDE];
            if (j == 0) val *= cscale[i*256 + tid];
            out[idx + (size_t)j * STRIDE] = val;
        }
    }
}

// ---------------- launcher ----------------
extern "C" void kernel_launch(void* const* d_in, const int* in_sizes, int n_in,
                              void* d_out, int out_size, void* d_ws, size_t ws_size,
                              hipStream_t stream)
{
    (void)in_sizes; (void)n_in; (void)out_size; (void)ws_size;
    const float* hidden         = (const float*)d_in[0];
    const float* cosp           = (const float*)d_in[1];
    const float* sinp           = (const float*)d_in[2];
    const float* wq             = (const float*)d_in[3];
    const float* wk             = (const float*)d_in[4];
    const float* wv             = (const float*)d_in[5];
    const float* wo             = (const float*)d_in[6];
    const float* q_norm_w       = (const float*)d_in[7];
    const float* k_norm_w       = (const float*)d_in[8];
    const float* input_ln_w     = (const float*)d_in[9];
    const float* post_attn_ln_w = (const float*)d_in[10];
    const float* pre_ffw_ln_w   = (const float*)d_in[11];
    const float* post_ffw_ln_w  = (const float*)d_in[12];
    const float* gate_w         = (const float*)d_in[13];
    const float* up_w           = (const float*)d_in[14];
    const float* down_w         = (const float*)d_in[15];
    const float* ll_w           = (const float*)d_in[16];
    const float* lr_w           = (const float*)d_in[17];
    const float* laurel_norm_w  = (const float*)d_in[18];
    const float* router_norm_w  = (const float*)d_in[19];
    const float* router_w       = (const float*)d_in[20];
    const float* pred_coef_w    = (const float*)d_in[21];
    const float* corr_coef_w    = (const float*)d_in[22];
    const float* cscale         = (const float*)d_in[23];
    float* outp = (float*)d_out;

    char* base = (char*)d_ws;
    float* pred   = (float*)base;              base += 67108864;   // [4,R,H] fp32
    float* xnorm  = (float*)base;              base += 16777216;   // also split-K partial
    unsigned short* xnorm_bf = (unsigned short*)base; base += 8388608;
    float* lout   = (float*)base;              base += 16777216;
    float* alaur  = (float*)base;              base += 16777216;
    float* tmpH   = (float*)base;              base += 16777216;
    float* mbuf   = (float*)base;              base += 32768;
    float* mcbuf  = (float*)base;              base += 32768;
    float* ltmp   = (float*)base;              base += 524288;
    char* arena = base;                        // 100,663,296 B
    // attention phase layout
    unsigned short* qkvw_bf = (unsigned short*)arena;                 // 12,582,912 B
    float* qkv_pre = (float*)(arena + 12582912);                      // 25,165,824 B (dead after rope)
    unsigned short* Pbuf    = (unsigned short*)arena;                 // 33,554,432 B (16 heads bf16, over dead qkvw/qkv_pre)
    unsigned short* q_bf    = (unsigned short*)(arena + 37748736);    //  8,388,608 B
    unsigned short* k_bf    = (unsigned short*)(arena + 46137344);    //  2,097,152 B
    unsigned short* vT_bf   = (unsigned short*)(arena + 48234496);    //  2,097,152 B
    unsigned short* attn_bf = (unsigned short*)(arena + 50331648);    //  8,388,608 B
    unsigned short* wo_bf   = (unsigned short*)(arena + 58720256);    //  8,388,608 B
    float* Sbuf             = (float*)(arena + 67108864);             // 33,554,432 B (8 heads fp32)
    // MLP phase layout (aliases attention phase)
    unsigned short* gate_bf = (unsigned short*)arena;
    unsigned short* up_bf   = (unsigned short*)(arena + 33554432);
    unsigned short* gu_bf   = (unsigned short*)(arena + 67108864);
    unsigned short* down_bf = gate_bf;
    float* activated = lout;

    // ---- AltUp predict ----
    router_kernel <<<ROWS_, 256, 0, stream>>>(hidden, router_norm_w, router_w, mbuf);
    predict_kernel<<<ROWS_, 256, 0, stream>>>(hidden, mbuf, pred_coef_w, pred);
    ln_residual   <<<ROWS_, 256, 0, stream>>>(pred, nullptr, input_ln_w, nullptr, nullptr, 1.f, xnorm, xnorm_bf);

    // ---- Laurel (fp32, small) ----
    gemm_nt<<<dim3(LR_/BN, ROWS_/BM), 256, 0, stream>>>(xnorm, ll_w, ltmp, ROWS_, LR_, H_);
    gemm_nt<<<dim3(H_/BN,  ROWS_/BM), 256, 0, stream>>>(ltmp, lr_w, tmpH, ROWS_, H_, LR_);
    ln_residual<<<ROWS_, 256, 0, stream>>>(tmpH, nullptr, laurel_norm_w, xnorm, nullptr, 1.f, lout, nullptr);

    // ---- Attention ----
    cvt_bf16<<<2048, 256, 0, stream>>>(wq, qkvw_bf,            4194304);
    cvt_bf16<<< 512, 256, 0, stream>>>(wk, qkvw_bf + 4194304,  1048576);
    cvt_bf16<<< 512, 256, 0, stream>>>(wv, qkvw_bf + 5242880,  1048576);
    gemm_bf16nt<<<dim3(24, 16, 1), 256, 0, stream>>>(xnorm_bf, qkvw_bf, qkv_pre, nullptr, ROWS_, 3072, H_);
    qkv_norm_rope_fused<<<ROWS_*12, 256, 0, stream>>>(qkv_pre, q_norm_w, k_norm_w, cosp, sinp, q_bf, k_bf, vT_bf);
    cvt_bf16<<<2048, 256, 0, stream>>>(wo, wo_bf, 4194304);
    for (int hb = 0; hb < B_ * NH_; hb += 8) {
        qk_gemm       <<<dim3(8, 8, 8), 256, 0, stream>>>(q_bf, k_bf, Sbuf, hb);
        softmax_causal<<<dim3(T_, 8),   256, 0, stream>>>(Sbuf, Pbuf + (size_t)hb * T_ * T_);
    }
    pv_gemm<<<dim3(2, 8, 16), 256, 0, stream>>>(Pbuf, vT_bf, attn_bf);
    gemm_bf16nt<<<dim3(16, 16, 2), 256, 0, stream>>>(attn_bf, wo_bf, tmpH, xnorm, ROWS_, H_, NH_*HD_);
    ln_residual<<<ROWS_, 256, 0, stream>>>(tmpH, xnorm, post_attn_ln_w, pred, lout, 0.7071067811865475f, alaur, nullptr);

    // ---- MLP ----
    ln_residual<<<ROWS_, 256, 0, stream>>>(alaur, nullptr, pre_ffw_ln_w, nullptr, nullptr, 1.f, nullptr, xnorm_bf);
    cvt_bf16<<<8192, 256, 0, stream>>>(gate_w, gate_bf, 16777216);
    cvt_bf16<<<8192, 256, 0, stream>>>(up_w,   up_bf,   16777216);
    gemm_gateup_bf16<<<dim3(64, 16), 256, 0, stream>>>(xnorm_bf, gate_bf, up_bf, gu_bf, ROWS_, FF_, H_);
    cvt_bf16<<<8192, 256, 0, stream>>>(down_w, down_bf, 16777216);
    gemm_bf16nt<<<dim3(16, 16, 2), 256, 0, stream>>>(gu_bf, down_bf, tmpH, xnorm, ROWS_, H_, FF_);
    ln_residual<<<ROWS_, 256, 0, stream>>>(tmpH, xnorm, post_ffw_ln_w, alaur, nullptr, 1.f, activated, nullptr);

    // ---- AltUp correct ----
    router_kernel <<<ROWS_, 256, 0, stream>>>(activated, router_norm_w, router_w, mcbuf);
    correct_kernel<<<ROWS_, 256, 0, stream>>>(activated, pred, mcbuf, corr_coef_w, cscale, outp);
}

// Round 6
// 1020.308 us; speedup vs baseline: 1.1783x; 1.0923x over previous
//
#include <hip/hip_runtime.h>
#include <hip/hip_bf16.h>
#include <math.h>

#define B_   2
#define T_   1024
#define H_   2048
#define NH_  8
#define NKV_ 2
#define HD_  256
#define S_   4
#define FF_  8192
#define LR_  64
#define ROWS_ (B_*T_)          // 2048 tokens
#define EPS_ 1e-6f

typedef __attribute__((ext_vector_type(8))) __bf16 bf16x8;
typedef __attribute__((ext_vector_type(4))) float floatx4;
typedef __attribute__((ext_vector_type(8))) unsigned short ushort8v;

__device__ __forceinline__ unsigned short f2bf(float f) {
    unsigned int u = __float_as_uint(f);
    return (unsigned short)((u + 0x7FFFu + ((u >> 16) & 1u)) >> 16);
}

// async global->LDS, 16B per lane. LDS dest is wave-uniform base + lane*16.
__device__ __forceinline__ void gl_lds16(const void* g, void* l) {
    __builtin_amdgcn_global_load_lds(
        (const __attribute__((address_space(1))) void*)g,
        (__attribute__((address_space(3))) void*)l, 16, 0, 0);
}

// LDS bank swizzle: physical 16B slot for (row, kc) = kc ^ sigma(row&15).
__device__ __forceinline__ int swz_sigma(int r15) {
    return (r15 & 3) ^ ((r15 >> 2) & 3);
}

// ---------------- block-wide reductions (256 threads = 4 waves) ----------------
__device__ __forceinline__ float block_sum(float v) {
    __shared__ float s4[4];
    #pragma unroll
    for (int o = 32; o > 0; o >>= 1) v += __shfl_down(v, o, 64);
    int lane = threadIdx.x & 63;
    int w    = threadIdx.x >> 6;
    __syncthreads();
    if (lane == 0) s4[w] = v;
    __syncthreads();
    return s4[0] + s4[1] + s4[2] + s4[3];
}

__device__ __forceinline__ float block_max(float v) {
    __shared__ float s4m[4];
    #pragma unroll
    for (int o = 32; o > 0; o >>= 1) v = fmaxf(v, __shfl_down(v, o, 64));
    int lane = threadIdx.x & 63;
    int w    = threadIdx.x >> 6;
    __syncthreads();
    if (lane == 0) s4m[w] = v;
    __syncthreads();
    return fmaxf(fmaxf(s4m[0], s4m[1]), fmaxf(s4m[2], s4m[3]));
}

// ---------------- fp32 -> bf16 convert (8 elements/thread) ----------------------
__global__ __launch_bounds__(256) void cvt_bf16(
    const float* __restrict__ in, unsigned short* __restrict__ out, int n)
{
    int i = (blockIdx.x * 256 + threadIdx.x) * 8;
    if (i >= n) return;
    float4 v0 = *reinterpret_cast<const float4*>(in + i);
    float4 v1 = *reinterpret_cast<const float4*>(in + i + 4);
    ushort8v o;
    o[0] = f2bf(v0.x); o[1] = f2bf(v0.y); o[2] = f2bf(v0.z); o[3] = f2bf(v0.w);
    o[4] = f2bf(v1.x); o[5] = f2bf(v1.y); o[6] = f2bf(v1.z); o[7] = f2bf(v1.w);
    *reinterpret_cast<ushort8v*>(out + i) = o;
}

// ---------------- router: m = tanh( (LN(x)*w_norm / H) @ router_w^T ) ----------
__global__ __launch_bounds__(256) void router_kernel(
    const float* __restrict__ x, const float* __restrict__ nw,
    const float* __restrict__ rw, float* __restrict__ mout)
{
    size_t row = blockIdx.x;
    int tid = threadIdx.x;
    const float* xr = x + row * H_;
    float v[8]; float s = 0.f;
    #pragma unroll
    for (int i = 0; i < 8; ++i) { v[i] = xr[i*256 + tid]; s += v[i]; }
    float mu = block_sum(s) * (1.f / H_);
    float ss = 0.f;
    #pragma unroll
    for (int i = 0; i < 8; ++i) { float c = v[i] - mu; ss += c * c; }
    float rstd = rsqrtf(block_sum(ss) * (1.f / H_) + EPS_);
    float n[8];
    #pragma unroll
    for (int i = 0; i < 8; ++i) n[i] = (v[i] - mu) * rstd * nw[i*256 + tid];
    for (int so = 0; so < S_; ++so) {
        float p = 0.f;
        #pragma unroll
        for (int i = 0; i < 8; ++i) p += n[i] * rw[(size_t)so * H_ + i*256 + tid];
        float dot = block_sum(p);
        if (tid == 0) mout[row * S_ + so] = tanhf(dot * (1.f / H_));
    }
}

// ---------------- altup predict ----------------
__global__ __launch_bounds__(256) void predict_kernel(
    const float* __restrict__ hid, const float* __restrict__ m,
    const float* __restrict__ pcw, float* __restrict__ pred)
{
    size_t row = blockIdx.x;
    int tid = threadIdx.x;
    __shared__ float ms[4];
    __shared__ float c[16];
    if (tid < 4) ms[tid] = m[row * S_ + tid];
    __syncthreads();
    if (tid < 16) {
        float s = 0.f;
        #pragma unroll
        for (int i = 0; i < 4; ++i) s += ms[i] * pcw[tid * 4 + i];
        c[tid] = s;
    }
    __syncthreads();
    const size_t STRIDE = (size_t)ROWS_ * H_;
    #pragma unroll
    for (int i = 0; i < 8; ++i) {
        size_t idx = row * H_ + i*256 + tid;
        float h0 = hid[idx];
        float h1 = hid[idx + STRIDE];
        float h2 = hid[idx + 2*STRIDE];
        float h3 = hid[idx + 3*STRIDE];
        float hv[4] = {h0, h1, h2, h3};
        #pragma unroll
        for (int j = 0; j < 4; ++j) {
            float val = hv[j] + h0*c[j*4+0] + h1*c[j*4+1] + h2*c[j*4+2] + h3*c[j*4+3];
            pred[idx + (size_t)j * STRIDE] = val;
        }
    }
}

// ---- LN (+ optional pre-add xadd, residuals a1/a2, scale, fp32/bf16 out) -------
__global__ __launch_bounds__(256) void ln_residual(
    const float* __restrict__ x, const float* __restrict__ xadd,
    const float* __restrict__ w,
    const float* __restrict__ a1, const float* __restrict__ a2,
    float scale, float* __restrict__ out, unsigned short* __restrict__ outb)
{
    size_t row = blockIdx.x;
    int tid = threadIdx.x;
    const float* xr = x + row * H_;
    const float* xa = xadd ? xadd + row * H_ : nullptr;
    float v[8]; float s = 0.f;
    #pragma unroll
    for (int i = 0; i < 8; ++i) {
        v[i] = xr[i*256 + tid];
        if (xa) v[i] += xa[i*256 + tid];
        s += v[i];
    }
    float mu = block_sum(s) * (1.f / H_);
    float ss = 0.f;
    #pragma unroll
    for (int i = 0; i < 8; ++i) { float c = v[i] - mu; ss += c * c; }
    float rstd = rsqrtf(block_sum(ss) * (1.f / H_) + EPS_);
    #pragma unroll
    for (int i = 0; i < 8; ++i) {
        size_t idx = row * H_ + i*256 + tid;
        float y = (v[i] - mu) * rstd * w[i*256 + tid];
        if (a1) y += a1[idx];
        if (a2) y += a2[idx];
        y *= scale;
        if (out)  out[idx]  = y;
        if (outb) outb[idx] = f2bf(y);
    }
}

// ---------------- fp32 GEMM (laurel only): C = A[M,K] * B[N,K]^T ----------------
#define BM 64
#define BN 64
#define BK 32
#define LDP 68

__global__ __launch_bounds__(256) void gemm_nt(
    const float* __restrict__ A, const float* __restrict__ Bm,
    float* __restrict__ C, int M, int N, int K)
{
    __shared__ float As[BK][LDP];
    __shared__ float Bs[BK][LDP];
    int tid = threadIdx.x;
    int n0 = blockIdx.x * BN;
    int m0 = blockIdx.y * BM;
    int tx = tid & 15, ty = tid >> 4;
    int lrow = tid >> 3;
    int lk   = (tid & 7) << 2;
    float acc[4][4] = {};
    for (int k0 = 0; k0 < K; k0 += BK) {
        #pragma unroll
        for (int r = 0; r < 2; ++r) {
            int row = lrow + r * 32;
            float4 a4 = *reinterpret_cast<const float4*>(&A[(size_t)(m0 + row) * K + k0 + lk]);
            As[lk+0][row] = a4.x; As[lk+1][row] = a4.y; As[lk+2][row] = a4.z; As[lk+3][row] = a4.w;
            float4 b4 = *reinterpret_cast<const float4*>(&Bm[(size_t)(n0 + row) * K + k0 + lk]);
            Bs[lk+0][row] = b4.x; Bs[lk+1][row] = b4.y; Bs[lk+2][row] = b4.z; Bs[lk+3][row] = b4.w;
        }
        __syncthreads();
        #pragma unroll
        for (int k = 0; k < BK; ++k) {
            float4 av = *reinterpret_cast<const float4*>(&As[k][ty << 2]);
            float4 bv = *reinterpret_cast<const float4*>(&Bs[k][tx << 2]);
            float a[4] = {av.x, av.y, av.z, av.w};
            float b[4] = {bv.x, bv.y, bv.z, bv.w};
            #pragma unroll
            for (int i = 0; i < 4; ++i)
                #pragma unroll
                for (int j = 0; j < 4; ++j)
                    acc[i][j] = fmaf(a[i], b[j], acc[i][j]);
        }
        __syncthreads();
    }
    #pragma unroll
    for (int i = 0; i < 4; ++i) {
        float4 o; o.x = acc[i][0]; o.y = acc[i][1]; o.z = acc[i][2]; o.w = acc[i][3];
        *reinterpret_cast<float4*>(&C[(size_t)(m0 + (ty << 2) + i) * N + n0 + (tx << 2)]) = o;
    }
}

// ---------------- bf16 MFMA GEMM, coalesced gl_lds + swizzle + dbuf -------------
// C[M,N] (fp32) = A_bf16[M,K] * B_bf16[N,K]^T.  128x128 tile, BK=32.
// grid.z = split-K: z==0 -> C, z==1 -> C2 (consumer sums).
__global__ __launch_bounds__(256) void gemm_bf16nt(
    const unsigned short* __restrict__ A, const unsigned short* __restrict__ Bm,
    float* __restrict__ C, float* __restrict__ C2, int M, int N, int K)
{
    __shared__ unsigned short As[8192];   // [2][128][32]
    __shared__ unsigned short Bs[8192];
    int tid = threadIdx.x;
    int lane = tid & 63;
    int wave = tid >> 6;
    int m0 = blockIdx.y * 128, n0 = blockIdx.x * 128;
    int Kper = K / gridDim.z;
    int kbeg = blockIdx.z * Kper;
    int kend = kbeg + Kper;
    int wm = (wave >> 1) * 64;
    int wn = (wave & 1) * 64;
    floatx4 acc[4][4] = {};

    int lr = lane >> 2;                      // row within 16-row group
    int kcs = (lane & 3) ^ swz_sigma(lr);    // global k-chunk this lane fetches
    const unsigned short* aG0 = A  + (size_t)(m0 + wave*16 + lr) * K + kcs * 8;
    const unsigned short* aG1 = aG0 + (size_t)64 * K;
    const unsigned short* bG0 = Bm + (size_t)(n0 + wave*16 + lr) * K + kcs * 8;
    const unsigned short* bG1 = bG0 + (size_t)64 * K;

    int kc = lane >> 4, mr = lane & 15;
    int kcp = (kc ^ swz_sigma(mr)) * 8;      // physical slot offset for reads

    // prologue: stage first tile into buf 0
    gl_lds16(aG0 + kbeg, &As[wave * 512]);
    gl_lds16(aG1 + kbeg, &As[2048 + wave * 512]);
    gl_lds16(bG0 + kbeg, &Bs[wave * 512]);
    gl_lds16(bG1 + kbeg, &Bs[2048 + wave * 512]);
    __syncthreads();
    int cur = 0;
    for (int k0 = kbeg; k0 < kend; k0 += 32) {
        if (k0 + 32 < kend) {           // prefetch next tile into other buffer
            int nb = (cur ^ 1) * 4096;
            gl_lds16(aG0 + k0 + 32, &As[nb + wave * 512]);
            gl_lds16(aG1 + k0 + 32, &As[nb + 2048 + wave * 512]);
            gl_lds16(bG0 + k0 + 32, &Bs[nb + wave * 512]);
            gl_lds16(bG1 + k0 + 32, &Bs[nb + 2048 + wave * 512]);
        }
        int cb = cur * 4096;
        bf16x8 af[4], bfv[4];
        #pragma unroll
        for (int mi = 0; mi < 4; ++mi)
            af[mi] = *reinterpret_cast<const bf16x8*>(&As[cb + (wm + mi * 16 + mr) * 32 + kcp]);
        #pragma unroll
        for (int ni = 0; ni < 4; ++ni)
            bfv[ni] = *reinterpret_cast<const bf16x8*>(&Bs[cb + (wn + ni * 16 + mr) * 32 + kcp]);
        #pragma unroll
        for (int mi = 0; mi < 4; ++mi)
            #pragma unroll
            for (int ni = 0; ni < 4; ++ni)
                acc[mi][ni] = __builtin_amdgcn_mfma_f32_16x16x32_bf16(af[mi], bfv[ni], acc[mi][ni], 0, 0, 0);
        __syncthreads();   // drains prefetch vmcnt + fences reads of cur
        cur ^= 1;
    }
    float* Cout = (blockIdx.z == 0) ? C : C2;
    int quad = lane >> 4;
    #pragma unroll
    for (int mi = 0; mi < 4; ++mi)
        #pragma unroll
        for (int ni = 0; ni < 4; ++ni)
            #pragma unroll
            for (int r = 0; r < 4; ++r)
                Cout[(size_t)(m0 + wm + mi * 16 + quad * 4 + r) * N + n0 + wn + ni * 16 + mr] = acc[mi][ni][r];
}

// ---------------- fused gate/up bf16 GEMM -> gu_bf16 = gelu(A*G^T)*(A*U^T) ------
// R0-proven version: reg-staged dbuf, BM=128, BN=64, LDS [kc:4][row][8] chunk-major.
// 4 waves each 32 rows x 64 cols. (215us / MfmaUtil 27.6% measured R0.)
__global__ __launch_bounds__(256) void gemm_gateup_bf16(
    const unsigned short* __restrict__ A, const unsigned short* __restrict__ G,
    const unsigned short* __restrict__ U, unsigned short* __restrict__ Cbf,
    int M, int N, int K)
{
    __shared__ unsigned short As[4096];  // [kc:4][m:128][8]
    __shared__ unsigned short Gs[2048];  // [kc:4][n:64][8]
    __shared__ unsigned short Us[2048];
    int tid = threadIdx.x;
    int lane = tid & 63;
    int wave = tid >> 6;
    int m0 = blockIdx.y * 128, n0 = blockIdx.x * 64;
    floatx4 accg[2][4] = {};
    floatx4 accu[2][4] = {};

    int cm = tid >> 2;
    int ck = tid & 3;
    const unsigned short* aP0 = A + (size_t)(m0 + cm)      * K + ck * 8;
    const unsigned short* aP1 = A + (size_t)(m0 + 64 + cm) * K + ck * 8;
    const unsigned short* gP  = G + (size_t)(n0 + cm)      * K + ck * 8;
    const unsigned short* uP  = U + (size_t)(n0 + cm)      * K + ck * 8;
    unsigned short* aW0 = &As[(ck * 128 + cm) * 8];
    unsigned short* aW1 = &As[(ck * 128 + 64 + cm) * 8];
    unsigned short* gW  = &Gs[(ck * 64 + cm) * 8];
    unsigned short* uW  = &Us[(ck * 64 + cm) * 8];

    uint4 ra0 = *reinterpret_cast<const uint4*>(aP0);
    uint4 ra1 = *reinterpret_cast<const uint4*>(aP1);
    uint4 rg  = *reinterpret_cast<const uint4*>(gP);
    uint4 ru  = *reinterpret_cast<const uint4*>(uP);

    int kc = lane >> 4, mr = lane & 15;
    for (int k0 = 0; k0 < K; k0 += 32) {
        __syncthreads();
        *reinterpret_cast<uint4*>(aW0) = ra0;
        *reinterpret_cast<uint4*>(aW1) = ra1;
        *reinterpret_cast<uint4*>(gW)  = rg;
        *reinterpret_cast<uint4*>(uW)  = ru;
        __syncthreads();
        if (k0 + 32 < K) {
            ra0 = *reinterpret_cast<const uint4*>(aP0 + k0 + 32);
            ra1 = *reinterpret_cast<const uint4*>(aP1 + k0 + 32);
            rg  = *reinterpret_cast<const uint4*>(gP + k0 + 32);
            ru  = *reinterpret_cast<const uint4*>(uP + k0 + 32);
        }
        bf16x8 af[2], gf[4], uf[4];
        #pragma unroll
        for (int mi = 0; mi < 2; ++mi)
            af[mi] = *reinterpret_cast<const bf16x8*>(&As[kc * 1024 + (wave * 32 + mi * 16 + mr) * 8]);
        #pragma unroll
        for (int ni = 0; ni < 4; ++ni) {
            gf[ni] = *reinterpret_cast<const bf16x8*>(&Gs[kc * 512 + (ni * 16 + mr) * 8]);
            uf[ni] = *reinterpret_cast<const bf16x8*>(&Us[kc * 512 + (ni * 16 + mr) * 8]);
        }
        #pragma unroll
        for (int mi = 0; mi < 2; ++mi)
            #pragma unroll
            for (int ni = 0; ni < 4; ++ni) {
                accg[mi][ni] = __builtin_amdgcn_mfma_f32_16x16x32_bf16(af[mi], gf[ni], accg[mi][ni], 0, 0, 0);
                accu[mi][ni] = __builtin_amdgcn_mfma_f32_16x16x32_bf16(af[mi], uf[ni], accu[mi][ni], 0, 0, 0);
            }
    }
    int quad = lane >> 4;
    #pragma unroll
    for (int mi = 0; mi < 2; ++mi) {
        int rb = m0 + wave * 32 + mi * 16 + quad * 4;
        #pragma unroll
        for (int ni = 0; ni < 4; ++ni)
            #pragma unroll
            for (int r = 0; r < 4; ++r) {
                float g = accg[mi][ni][r];
                float gl = 0.5f * g * (1.f + tanhf(0.7978845608028654f * (g + 0.044715f * g * g * g)));
                float val = gl * accu[mi][ni][r];
                Cbf[(size_t)(rb + r) * N + n0 + ni * 16 + mr] = f2bf(val);
            }
    }
}

// ---------------- fused per-head LN + RoPE for q/k/v, bf16 out ------------------
// grid = ROWS_*12 ; hh: 0-7 = q heads, 8-9 = k heads, 10-11 = v heads (v transposed)
__global__ __launch_bounds__(256) void qkv_norm_rope_fused(
    const float* __restrict__ in, const float* __restrict__ qw,
    const float* __restrict__ kw,
    const float* __restrict__ cs, const float* __restrict__ sn,
    unsigned short* __restrict__ qo, unsigned short* __restrict__ ko,
    unsigned short* __restrict__ vo)
{
    int blk = blockIdx.x;
    int hh = blk % 12;
    int trow = blk / 12;
    int b = trow / T_;
    int t = trow % T_;
    int d = threadIdx.x;
    float x = in[(size_t)trow * 3072 + hh * HD_ + d];
    float mu = block_sum(x) * (1.f / HD_);
    float xc = x - mu;
    float var = block_sum(xc * xc) * (1.f / HD_);
    float wv_ = (hh < 8) ? qw[d] : (hh < 10 ? kw[d] : 1.f);
    float n = xc * rsqrtf(var + EPS_) * wv_;
    __shared__ float buf[HD_];
    buf[d] = n;
    __syncthreads();
    float val = n;
    if (hh < 10) {   // rope for q and k (block-uniform branch)
        float c = cs[(size_t)trow * HD_ + d];
        float s = sn[(size_t)trow * HD_ + d];
        float other = (d < 128) ? -buf[d + 128] : buf[d - 128];
        val = n * c + other * s;
    }
    if (hh < 8)
        qo[(((size_t)b * NH_ + hh) * T_ + t) * HD_ + d] = f2bf(val);
    else if (hh < 10)
        ko[(((size_t)b * NKV_ + (hh - 8)) * T_ + t) * HD_ + d] = f2bf(val);
    else
        vo[(((size_t)b * NKV_ + (hh - 10)) * HD_ + d) * T_ + t] = f2bf(val);
}

// ---------------- QK^T batched bf16 MFMA GEMM (causal tile-skip) ----------------
// Q: [16 heads][T,HD]; K: [4 kv][T,HD]; S: [8 heads of group][T,T] fp32
// grid (T/128, T/128, 8). Swizzled LDS.
__global__ __launch_bounds__(256) void qk_gemm(
    const unsigned short* __restrict__ Q, const unsigned short* __restrict__ Kt,
    float* __restrict__ S, int head_base)
{
    if (blockIdx.x > blockIdx.y) return;   // tile fully above causal diagonal
    int z = blockIdx.z;
    int bh = head_base + z;
    const unsigned short* A  = Q  + (size_t)bh * T_ * HD_;
    const unsigned short* Bm = Kt + (size_t)(bh >> 2) * T_ * HD_;
    float* C = S + (size_t)z * T_ * T_;

    __shared__ unsigned short As[8192];
    __shared__ unsigned short Bs[8192];
    int tid = threadIdx.x;
    int lane = tid & 63;
    int wave = tid >> 6;
    int m0 = blockIdx.y * 128, n0 = blockIdx.x * 128;
    int wm = (wave >> 1) * 64;
    int wn = (wave & 1) * 64;
    floatx4 acc[4][4] = {};

    int lr = lane >> 2;
    int kcs = (lane & 3) ^ swz_sigma(lr);
    const unsigned short* aG0 = A  + (size_t)(m0 + wave*16 + lr) * HD_ + kcs * 8;
    const unsigned short* aG1 = aG0 + (size_t)64 * HD_;
    const unsigned short* bG0 = Bm + (size_t)(n0 + wave*16 + lr) * HD_ + kcs * 8;
    const unsigned short* bG1 = bG0 + (size_t)64 * HD_;

    int kc = lane >> 4, mr = lane & 15;
    int kcp = (kc ^ swz_sigma(mr)) * 8;

    gl_lds16(aG0, &As[wave * 512]);
    gl_lds16(aG1, &As[2048 + wave * 512]);
    gl_lds16(bG0, &Bs[wave * 512]);
    gl_lds16(bG1, &Bs[2048 + wave * 512]);
    __syncthreads();
    int cur = 0;
    for (int k0 = 0; k0 < HD_; k0 += 32) {
        if (k0 + 32 < HD_) {
            int nb = (cur ^ 1) * 4096;
            gl_lds16(aG0 + k0 + 32, &As[nb + wave * 512]);
            gl_lds16(aG1 + k0 + 32, &As[nb + 2048 + wave * 512]);
            gl_lds16(bG0 + k0 + 32, &Bs[nb + wave * 512]);
            gl_lds16(bG1 + k0 + 32, &Bs[nb + 2048 + wave * 512]);
        }
        int cb = cur * 4096;
        bf16x8 af[4], bfv[4];
        #pragma unroll
        for (int mi = 0; mi < 4; ++mi)
            af[mi] = *reinterpret_cast<const bf16x8*>(&As[cb + (wm + mi * 16 + mr) * 32 + kcp]);
        #pragma unroll
        for (int ni = 0; ni < 4; ++ni)
            bfv[ni] = *reinterpret_cast<const bf16x8*>(&Bs[cb + (wn + ni * 16 + mr) * 32 + kcp]);
        #pragma unroll
        for (int mi = 0; mi < 4; ++mi)
            #pragma unroll
            for (int ni = 0; ni < 4; ++ni)
                acc[mi][ni] = __builtin_amdgcn_mfma_f32_16x16x32_bf16(af[mi], bfv[ni], acc[mi][ni], 0, 0, 0);
        __syncthreads();
        cur ^= 1;
    }
    int quad = lane >> 4;
    #pragma unroll
    for (int mi = 0; mi < 4; ++mi)
        #pragma unroll
        for (int ni = 0; ni < 4; ++ni)
            #pragma unroll
            for (int r = 0; r < 4; ++r)
                C[(size_t)(m0 + wm + mi * 16 + quad * 4 + r) * T_ + n0 + wn + ni * 16 + mr] = acc[mi][ni][r];
}

// ---------------- causal softmax: fp32 scores row -> bf16 probs row -------------
// grid (T, 8): x=query row, y=head-in-group. Writes zeros above diagonal.
__global__ __launch_bounds__(256) void softmax_causal(
    const float* __restrict__ S, unsigned short* __restrict__ P)
{
    int qi = blockIdx.x;
    int g  = blockIdx.y;
    int tid = threadIdx.x;
    int L = qi + 1;
    const float* Srow = S + ((size_t)g * T_ + qi) * T_;
    unsigned short* Prow = P + ((size_t)g * T_ + qi) * T_;
    float v[4];
    float mx = -3.402823466e38f;
    #pragma unroll
    for (int i = 0; i < 4; ++i) {
        int idx = i * 256 + tid;
        v[i] = (idx < L) ? Srow[idx] : -3.402823466e38f;
        mx = fmaxf(mx, v[i]);
    }
    mx = block_max(mx);
    float sm = 0.f;
    float e[4];
    #pragma unroll
    for (int i = 0; i < 4; ++i) {
        int idx = i * 256 + tid;
        e[i] = (idx < L) ? expf(v[i] - mx) : 0.f;
        sm += e[i];
    }
    sm = block_sum(sm);
    float inv = 1.f / sm;
    #pragma unroll
    for (int i = 0; i < 4; ++i)
        Prow[i * 256 + tid] = f2bf(e[i] * inv);
}

// ---------------- PV batched bf16 MFMA GEMM (causal K early-exit) ---------------
// P: [16][T,T] bf16; Vt: [4 kv][HD,T] bf16; out bf16 [B*T, NH*HD]
// grid (HD/128=2, T/128=8, 16). Swizzled LDS.
__global__ __launch_bounds__(256) void pv_gemm(
    const unsigned short* __restrict__ P, const unsigned short* __restrict__ Vt,
    unsigned short* __restrict__ Out)
{
    int z = blockIdx.z;
    int b = z >> 3;
    int h = z & 7;
    const unsigned short* A  = P  + (size_t)z * T_ * T_;
    const unsigned short* Bm = Vt + (size_t)(z >> 2) * HD_ * T_;

    __shared__ unsigned short As[8192];
    __shared__ unsigned short Bs[8192];
    int tid = threadIdx.x;
    int lane = tid & 63;
    int wave = tid >> 6;
    int m0 = blockIdx.y * 128, n0 = blockIdx.x * 128;
    int Kend = m0 + 128;      // rows in this tile only attend keys < m0+128
    int wm = (wave >> 1) * 64;
    int wn = (wave & 1) * 64;
    floatx4 acc[4][4] = {};

    int lr = lane >> 2;
    int kcs = (lane & 3) ^ swz_sigma(lr);
    const unsigned short* aG0 = A  + (size_t)(m0 + wave*16 + lr) * T_ + kcs * 8;
    const unsigned short* aG1 = aG0 + (size_t)64 * T_;
    const unsigned short* bG0 = Bm + (size_t)(n0 + wave*16 + lr) * T_ + kcs * 8;
    const unsigned short* bG1 = bG0 + (size_t)64 * T_;

    int kc = lane >> 4, mr = lane & 15;
    int kcp = (kc ^ swz_sigma(mr)) * 8;

    gl_lds16(aG0, &As[wave * 512]);
    gl_lds16(aG1, &As[2048 + wave * 512]);
    gl_lds16(bG0, &Bs[wave * 512]);
    gl_lds16(bG1, &Bs[2048 + wave * 512]);
    __syncthreads();
    int cur = 0;
    for (int k0 = 0; k0 < Kend; k0 += 32) {
        if (k0 + 32 < Kend) {
            int nb = (cur ^ 1) * 4096;
            gl_lds16(aG0 + k0 + 32, &As[nb + wave * 512]);
            gl_lds16(aG1 + k0 + 32, &As[nb + 2048 + wave * 512]);
            gl_lds16(bG0 + k0 + 32, &Bs[nb + wave * 512]);
            gl_lds16(bG1 + k0 + 32, &Bs[nb + 2048 + wave * 512]);
        }
        int cb = cur * 4096;
        bf16x8 af[4], bfv[4];
        #pragma unroll
        for (int mi = 0; mi < 4; ++mi)
            af[mi] = *reinterpret_cast<const bf16x8*>(&As[cb + (wm + mi * 16 + mr) * 32 + kcp]);
        #pragma unroll
        for (int ni = 0; ni < 4; ++ni)
            bfv[ni] = *reinterpret_cast<const bf16x8*>(&Bs[cb + (wn + ni * 16 + mr) * 32 + kcp]);
        #pragma unroll
        for (int mi = 0; mi < 4; ++mi)
            #pragma unroll
            for (int ni = 0; ni < 4; ++ni)
                acc[mi][ni] = __builtin_amdgcn_mfma_f32_16x16x32_bf16(af[mi], bfv[ni], acc[mi][ni], 0, 0, 0);
        __syncthreads();
        cur ^= 1;
    }
    int quad = lane >> 4;
    #pragma unroll
    for (int mi = 0; mi < 4; ++mi)
        #pragma unroll
        for (int ni = 0; ni < 4; ++ni)
            #pragma unroll
            for (int r = 0; r < 4; ++r) {
                int row = m0 + wm + mi * 16 + quad * 4 + r;
                int col = n0 + wn + ni * 16 + mr;
                Out[((size_t)(b * T_ + row)) * (NH_ * HD_) + h * HD_ + col] =
                    f2bf(acc[mi][ni][r]);
            }
}

// ---------------- altup correct + output-scale on stream 0 ----------------------
__global__ __launch_bounds__(256) void correct_kernel(
    const float* __restrict__ act, const float* __restrict__ pred,
    const float* __restrict__ mc, const float* __restrict__ ccw,
    const float* __restrict__ cscale, float* __restrict__ out)
{
    size_t row = blockIdx.x;
    int tid = threadIdx.x;
    __shared__ float ms[4];
    __shared__ float cc[4];
    if (tid < 4) ms[tid] = mc[row * S_ + tid];
    __syncthreads();
    if (tid < 4) {
        float s = 1.f;
        #pragma unroll
        for (int i = 0; i < 4; ++i) s += ms[i] * ccw[tid * 4 + i];
        cc[tid] = s;
    }
    __syncthreads();
    const size_t STRIDE = (size_t)ROWS_ * H_;
    #pragma unroll
    for (int i = 0; i < 8; ++i) {
        size_t idx = row * H_ + i*256 + tid;
        float a  = act[idx];
        float p0 = pred[idx];
        float inn = a - p0;
        #pragma unroll
        for (int j = 0; j < 4; ++j) {
            float val = inn * cc[j] + pred[idx + (size_t)j * STRIDE];
            if (j == 0) val *= cscale[i*256 + tid];
            out[idx + (size_t)j * STRIDE] = val;
        }
    }
}

// ---------------- launcher ----------------
extern "C" void kernel_launch(void* const* d_in, const int* in_sizes, int n_in,
                              void* d_out, int out_size, void* d_ws, size_t ws_size,
                              hipStream_t stream)
{
    (void)in_sizes; (void)n_in; (void)out_size; (void)ws_size;
    const float* hidden         = (const float*)d_in[0];
    const float* cosp           = (const float*)d_in[1];
    const float* sinp           = (const float*)d_in[2];
    const float* wq             = (const float*)d_in[3];
    const float* wk             = (const float*)d_in[4];
    const float* wv             = (const float*)d_in[5];
    const float* wo             = (const float*)d_in[6];
    const float* q_norm_w       = (const float*)d_in[7];
    const float* k_norm_w       = (const float*)d_in[8];
    const float* input_ln_w     = (const float*)d_in[9];
    const float* post_attn_ln_w = (const float*)d_in[10];
    const float* pre_ffw_ln_w   = (const float*)d_in[11];
    const float* post_ffw_ln_w  = (const float*)d_in[12];
    const float* gate_w         = (const float*)d_in[13];
    const float* up_w           = (const float*)d_in[14];
    const float* down_w         = (const float*)d_in[15];
    const float* ll_w           = (const float*)d_in[16];
    const float* lr_w           = (const float*)d_in[17];
    const float* laurel_norm_w  = (const float*)d_in[18];
    const float* router_norm_w  = (const float*)d_in[19];
    const float* router_w       = (const float*)d_in[20];
    const float* pred_coef_w    = (const float*)d_in[21];
    const float* corr_coef_w    = (const float*)d_in[22];
    const float* cscale         = (const float*)d_in[23];
    float* outp = (float*)d_out;

    char* base = (char*)d_ws;
    float* pred   = (float*)base;              base += 67108864;   // [4,R,H] fp32
    float* xnorm  = (float*)base;              base += 16777216;   // also split-K partial
    unsigned short* xnorm_bf = (unsigned short*)base; base += 8388608;
    float* lout   = (float*)base;              base += 16777216;
    float* alaur  = (float*)base;              base += 16777216;
    float* tmpH   = (float*)base;              base += 16777216;
    float* mbuf   = (float*)base;              base += 32768;
    float* mcbuf  = (float*)base;              base += 32768;
    float* ltmp   = (float*)base;              base += 524288;
    char* arena = base;                        // 100,663,296 B
    // attention phase layout
    unsigned short* qkvw_bf = (unsigned short*)arena;                 // 12,582,912 B
    float* qkv_pre = (float*)(arena + 12582912);                      // 25,165,824 B (dead after rope)
    unsigned short* Pbuf    = (unsigned short*)arena;                 // 33,554,432 B (16 heads bf16, over dead qkvw/qkv_pre)
    unsigned short* q_bf    = (unsigned short*)(arena + 37748736);    //  8,388,608 B
    unsigned short* k_bf    = (unsigned short*)(arena + 46137344);    //  2,097,152 B
    unsigned short* vT_bf   = (unsigned short*)(arena + 48234496);    //  2,097,152 B
    unsigned short* attn_bf = (unsigned short*)(arena + 50331648);    //  8,388,608 B
    unsigned short* wo_bf   = (unsigned short*)(arena + 58720256);    //  8,388,608 B
    float* Sbuf             = (float*)(arena + 67108864);             // 33,554,432 B (8 heads fp32)
    // MLP phase layout (aliases attention phase)
    unsigned short* gate_bf = (unsigned short*)arena;
    unsigned short* up_bf   = (unsigned short*)(arena + 33554432);
    unsigned short* gu_bf   = (unsigned short*)(arena + 67108864);
    unsigned short* down_bf = gate_bf;
    float* activated = lout;

    // ---- AltUp predict ----
    router_kernel <<<ROWS_, 256, 0, stream>>>(hidden, router_norm_w, router_w, mbuf);
    predict_kernel<<<ROWS_, 256, 0, stream>>>(hidden, mbuf, pred_coef_w, pred);
    ln_residual   <<<ROWS_, 256, 0, stream>>>(pred, nullptr, input_ln_w, nullptr, nullptr, 1.f, xnorm, xnorm_bf);

    // ---- Laurel (fp32, small) ----
    gemm_nt<<<dim3(LR_/BN, ROWS_/BM), 256, 0, stream>>>(xnorm, ll_w, ltmp, ROWS_, LR_, H_);
    gemm_nt<<<dim3(H_/BN,  ROWS_/BM), 256, 0, stream>>>(ltmp, lr_w, tmpH, ROWS_, H_, LR_);
    ln_residual<<<ROWS_, 256, 0, stream>>>(tmpH, nullptr, laurel_norm_w, xnorm, nullptr, 1.f, lout, nullptr);

    // ---- Attention ----
    cvt_bf16<<<2048, 256, 0, stream>>>(wq, qkvw_bf,            4194304);
    cvt_bf16<<< 512, 256, 0, stream>>>(wk, qkvw_bf + 4194304,  1048576);
    cvt_bf16<<< 512, 256, 0, stream>>>(wv, qkvw_bf + 5242880,  1048576);
    gemm_bf16nt<<<dim3(24, 16, 1), 256, 0, stream>>>(xnorm_bf, qkvw_bf, qkv_pre, nullptr, ROWS_, 3072, H_);
    qkv_norm_rope_fused<<<ROWS_*12, 256, 0, stream>>>(qkv_pre, q_norm_w, k_norm_w, cosp, sinp, q_bf, k_bf, vT_bf);
    cvt_bf16<<<2048, 256, 0, stream>>>(wo, wo_bf, 4194304);
    for (int hb = 0; hb < B_ * NH_; hb += 8) {
        qk_gemm       <<<dim3(8, 8, 8), 256, 0, stream>>>(q_bf, k_bf, Sbuf, hb);
        softmax_causal<<<dim3(T_, 8),   256, 0, stream>>>(Sbuf, Pbuf + (size_t)hb * T_ * T_);
    }
    pv_gemm<<<dim3(2, 8, 16), 256, 0, stream>>>(Pbuf, vT_bf, attn_bf);
    gemm_bf16nt<<<dim3(16, 16, 2), 256, 0, stream>>>(attn_bf, wo_bf, tmpH, xnorm, ROWS_, H_, NH_*HD_);
    ln_residual<<<ROWS_, 256, 0, stream>>>(tmpH, xnorm, post_attn_ln_w, pred, lout, 0.7071067811865475f, alaur, nullptr);

    // ---- MLP ----
    ln_residual<<<ROWS_, 256, 0, stream>>>(alaur, nullptr, pre_ffw_ln_w, nullptr, nullptr, 1.f, nullptr, xnorm_bf);
    cvt_bf16<<<8192, 256, 0, stream>>>(gate_w, gate_bf, 16777216);
    cvt_bf16<<<8192, 256, 0, stream>>>(up_w,   up_bf,   16777216);
    gemm_gateup_bf16<<<dim3(128, 16), 256, 0, stream>>>(xnorm_bf, gate_bf, up_bf, gu_bf, ROWS_, FF_, H_);
    cvt_bf16<<<8192, 256, 0, stream>>>(down_w, down_bf, 16777216);
    gemm_bf16nt<<<dim3(16, 16, 2), 256, 0, stream>>>(gu_bf, down_bf, tmpH, xnorm, ROWS_, H_, FF_);
    ln_residual<<<ROWS_, 256, 0, stream>>>(tmpH, xnorm, post_ffw_ln_w, alaur, nullptr, 1.f, activated, nullptr);

    // ---- AltUp correct ----
    router_kernel <<<ROWS_, 256, 0, stream>>>(activated, router_norm_w, router_w, mcbuf);
    correct_kernel<<<ROWS_, 256, 0, stream>>>(activated, pred, mcbuf, corr_coef_w, cscale, outp);
}